// Round 11
// baseline (30184.436 us; speedup 1.0000x reference)
//
#include <hip/hip_runtime.h>

#define B_ 512
#define S_ 128
#define T_ 128
#define D_ 512
#define V_ 128
#define LDW 72

typedef __attribute__((ext_vector_type(8))) short s16x8;
typedef __attribute__((ext_vector_type(4))) short s16x4;
typedef __attribute__((ext_vector_type(4))) float f32x4;

__device__ __forceinline__ float b2f(unsigned short h) {
    union { unsigned int u; float f; } x; x.u = ((unsigned int)h) << 16; return x.f;
}
__device__ __forceinline__ unsigned short f2b(float f) {
    union { float f; unsigned int u; } x; x.f = f;
    unsigned int u = x.u; u += 0x7FFFu + ((u >> 16) & 1u);
    return (unsigned short)(u >> 16);
}
#if __has_builtin(__builtin_amdgcn_rcpf)
__device__ __forceinline__ float rcp_f(float x) { return __builtin_amdgcn_rcpf(x); }
#else
__device__ __forceinline__ float rcp_f(float x) { return 1.0f / x; }
#endif
__device__ __forceinline__ float sigm(float x) { return rcp_f(1.0f + __expf(-x)); }
__device__ __forceinline__ float tanh_fast(float x) {
    float e = __expf(2.0f * fabsf(x));
    float r = 1.0f - 2.0f * rcp_f(e + 1.0f);
    return copysignf(r, x);
}
// Pade[3/2] tanh: max |err| ~7e-4 with clamp; 1 rcp, no exp.
__device__ __forceinline__ float tanh_pade(float x) {
    float t = x * x;
    float num = x * fmaf(t, 105.0f + t, 945.0f);
    float den = fmaf(t, fmaf(t, 15.0f, 420.0f), 945.0f);
    float r = num * rcp_f(den);
    return fminf(1.0f, fmaxf(-1.0f, r));
}

// ---------------- fp8 (OCP e4m3) encode/decode ----------------
#if __has_builtin(__builtin_amdgcn_cvt_f32_fp8)
__device__ __forceinline__ f32x4 fp8x4_dec(unsigned w) {
    f32x4 r;
    r[0] = __builtin_amdgcn_cvt_f32_fp8(w, 0);
    r[1] = __builtin_amdgcn_cvt_f32_fp8(w, 1);
    r[2] = __builtin_amdgcn_cvt_f32_fp8(w, 2);
    r[3] = __builtin_amdgcn_cvt_f32_fp8(w, 3);
    return r;
}
#else
__device__ __forceinline__ float fp8_dec_sw(unsigned w, int j) {
    unsigned char v = (w >> (8 * j)) & 0xFF;
    unsigned s = v >> 7, e = (v >> 3) & 0xF, m = v & 7;
    float r = (e == 0) ? ldexpf((float)m, -9) : ldexpf((float)(8 + m), (int)e - 10);
    return s ? -r : r;
}
__device__ __forceinline__ f32x4 fp8x4_dec(unsigned w) {
    f32x4 r;
    r[0] = fp8_dec_sw(w, 0); r[1] = fp8_dec_sw(w, 1);
    r[2] = fp8_dec_sw(w, 2); r[3] = fp8_dec_sw(w, 3);
    return r;
}
#endif

#if __has_builtin(__builtin_amdgcn_cvt_pk_fp8_f32)
__device__ __forceinline__ unsigned pk_fp8(float a, float b, float c, float d) {
    int r = 0;
    r = __builtin_amdgcn_cvt_pk_fp8_f32(a, b, r, false);
    r = __builtin_amdgcn_cvt_pk_fp8_f32(c, d, r, true);
    return (unsigned)r;
}
#else
__device__ __forceinline__ unsigned char f32_to_fp8_sw(float x) {
    unsigned s = x < 0.f ? 0x80u : 0u; float a = fabsf(x);
    if (a != a) return (unsigned char)(s | 0x7F);
    if (a >= 448.f) return (unsigned char)(s | 0x7E);
    if (a < 0.001953125f) { int m = (int)rintf(a * 512.0f); return (unsigned char)(s | (m > 7 ? 0x08 : m)); }
    int e; float fr = frexpf(a, &e);
    int m = (int)rintf(fr * 16.0f - 8.0f);
    int ee = e - 1 + 7;
    if (m == 8) { m = 0; ee += 1; }
    if (ee <= 0) { int mm = (int)rintf(a * 512.f); return (unsigned char)(s | (mm > 7 ? 0x08 : mm)); }
    if (ee >= 16) return (unsigned char)(s | 0x7E);
    return (unsigned char)(s | (ee << 3) | m);
}
__device__ __forceinline__ unsigned pk_fp8(float a, float b, float c, float d) {
    return (unsigned)f32_to_fp8_sw(a) | ((unsigned)f32_to_fp8_sw(b) << 8)
         | ((unsigned)f32_to_fp8_sw(c) << 16) | ((unsigned)f32_to_fp8_sw(d) << 24);
}
#endif

struct P {
    const int* target;
    const float* E; const float* bv; const float* ba; const float* bout; const float* bcat;
    const short* vab;
    const unsigned char* ea8; const unsigned char* kp8;
    const short* WaT; const short* WehT; const short* WctxT; const short* WoutT;
    short* qbf; short* ctxb; short* gp;
    float* cst; short* hcbf; short* xehg;
    float* out_logits; float* out_attn;
};

// ================= kA: attention, 512 blocks (1 row each) =================
__global__ __launch_bounds__(256, 2) void kA(P p, int step)
{
    __shared__ float scp[4][64];
    __shared__ float wbuf[S_];
    __shared__ float cpart[4][D_];
    const int b = blockIdx.x;
    const int t = threadIdx.x, lane = t & 63, wave = t >> 6;
    {
        const int sg = wave & 1, dh = wave >> 1;
        const int s = sg * 64 + lane;
        const unsigned char* kb = p.kp8 + (size_t)b * (S_ * D_);
        const short* qv = p.qbf + (size_t)b * D_;
        float acc = 0.f;
        #pragma unroll 4
        for (int i = 0; i < 16; ++i) {
            int g = dh * 16 + i;
            uint4 kw = *(const uint4*)(kb + ((size_t)g * 128 + s) * 16);
            const short* qg = qv + g * 16;
            const short* vg = p.vab + g * 16;
            s16x8 q0 = *(const s16x8*)(qg), q1 = *(const s16x8*)(qg + 8);
            s16x8 v0 = *(const s16x8*)(vg), v1 = *(const s16x8*)(vg + 8);
            f32x4 ka = fp8x4_dec(kw.x), kb4 = fp8x4_dec(kw.y);
            f32x4 kc = fp8x4_dec(kw.z), kd = fp8x4_dec(kw.w);
            #pragma unroll
            for (int j = 0; j < 4; ++j) {
                acc += tanh_pade(b2f((unsigned short)q0[j])     + ka[j])  * b2f((unsigned short)v0[j]);
                acc += tanh_pade(b2f((unsigned short)q0[4 + j]) + kb4[j]) * b2f((unsigned short)v0[4 + j]);
                acc += tanh_pade(b2f((unsigned short)q1[j])     + kc[j])  * b2f((unsigned short)v1[j]);
                acc += tanh_pade(b2f((unsigned short)q1[4 + j]) + kd[j])  * b2f((unsigned short)v1[4 + j]);
            }
        }
        scp[wave][lane] = acc;
    }
    __syncthreads();
    if (wave == 0) {
        const float bvv = p.bv[0];
        float v0 = scp[0][lane] + scp[2][lane] + bvv;
        float v1 = scp[1][lane] + scp[3][lane] + bvv;
        float m = fmaxf(v0, v1);
        #pragma unroll
        for (int o = 32; o >= 1; o >>= 1) m = fmaxf(m, __shfl_xor(m, o));
        float e0 = __expf(v0 - m), e1 = __expf(v1 - m);
        float su = e0 + e1;
        #pragma unroll
        for (int o = 32; o >= 1; o >>= 1) su += __shfl_xor(su, o);
        float inv = rcp_f(su);
        float w0 = e0 * inv, w1 = e1 * inv;
        wbuf[lane] = w0; wbuf[lane + 64] = w1;
        float* ao = p.out_attn + ((size_t)b * T_ + step) * S_;
        ao[lane] = w0; ao[lane + 64] = w1;
    }
    __syncthreads();
    {
        const int d0 = lane * 8;
        f32x4 aA = {0.f,0.f,0.f,0.f}, aB = {0.f,0.f,0.f,0.f};
        const unsigned char* eb = p.ea8 + (size_t)b * S_ * D_ + d0;
        #pragma unroll 4
        for (int i = 0; i < 32; ++i) {
            int s = wave * 32 + i;
            float wv = wbuf[s];
            uint2 ev = *(const uint2*)(eb + (size_t)s * D_);
            f32x4 ex = fp8x4_dec(ev.x), ey = fp8x4_dec(ev.y);
            #pragma unroll
            for (int j = 0; j < 4; ++j) aA[j] += wv * ex[j];
            #pragma unroll
            for (int j = 0; j < 4; ++j) aB[j] += wv * ey[j];
        }
        *(f32x4*)&cpart[wave][d0]     = aA;
        *(f32x4*)&cpart[wave][d0 + 4] = aB;
    }
    __syncthreads();
    {
        int dd = t * 2;
        float v0 = cpart[0][dd]   + cpart[1][dd]   + cpart[2][dd]   + cpart[3][dd];
        float v1 = cpart[0][dd+1] + cpart[1][dd+1] + cpart[2][dd+1] + cpart[3][dd+1];
        short2 o2; o2.x = (short)f2b(v0); o2.y = (short)f2b(v1);
        *(short2*)(p.ctxb + (size_t)b * D_ + dd) = o2;
    }
}

// ====== kE: 32 blocks x 16 rows, row-local fgate+LSTM+q+out+pgate (no cross-block deps) ======
#define MFMA_B(a, b, c) __builtin_amdgcn_mfma_f32_16x16x32_bf16((a), (b), (c), 0, 0, 0)

template<bool INIT>
__global__ __launch_bounds__(256)
void kE(P p, int step)
{
    __shared__ short ctx_l[16][520];
    __shared__ short hcl[16][520];
    __shared__ short xehl[16][1048];
    __shared__ float gtl[4][16][68];
    __shared__ float lgl[16][132];
    const int t = threadIdx.x, lane = t & 63, wave = t >> 6;
    const int lrow = lane & 15, kq = lane >> 4;
    const int r0 = blockIdx.x * 16;

    if (INIT) {
        for (int i = t; i < 16 * 64; i += 256) {
            int r = i >> 6, c8 = i & 63;
            *(s16x8*)&hcl[r][c8 * 8] = *(const s16x8*)(p.hcbf + (size_t)(r0 + r) * 512 + c8 * 8);
        }
        for (int i = t; i < 16 * 128; i += 256) {
            int r = i >> 7, c8 = i & 127;
            *(s16x8*)&xehl[r][c8 * 8] = *(const s16x8*)(p.xehg + (size_t)(r0 + r) * 1024 + c8 * 8);
        }
        __syncthreads();
    } else {
        // stage emb(target[.,step]) -> xehl[:,0..511]; ctx -> LDS
        for (int i = t; i < 16 * 512; i += 256) {
            int r = i >> 9, d = i & 511;
            int tok = p.target[(r0 + r) * T_ + step];
            xehl[r][d] = (short)f2b(p.E[(size_t)tok * 512 + d]);
        }
        for (int i = t; i < 16 * 64; i += 256) {
            int r = i >> 6, c8 = i & 63;
            *(s16x8*)&ctx_l[r][c8 * 8] = *(const s16x8*)(p.ctxb + (size_t)(r0 + r) * 512 + c8 * 8);
        }
        __syncthreads();
        // ---- fgate (wave covers gate cols wave*512..+511) + fused LSTM ----
        const int cw = wave * 512;
        s16x8 af[16];
        #pragma unroll
        for (int k0 = 0; k0 < 16; ++k0)
            af[k0] = *(const s16x8*)&ctx_l[lrow][k0 * 32 + kq * 8];
        for (int ng = 0; ng < 8; ++ng) {                       // groups of 4 n-tiles
            const int gn0 = cw + ng * 64;
            f32x4 acc[4] = {};
            #pragma unroll
            for (int k0 = 0; k0 < 16; ++k0) {
                #pragma unroll
                for (int u = 0; u < 4; ++u) {
                    s16x8 bf = *(const s16x8*)(p.WctxT + (size_t)(gn0 + u * 16 + lrow) * 512 + k0 * 32 + kq * 8);
                    acc[u] = MFMA_B(af[k0], bf, acc[u]);
                }
            }
            #pragma unroll
            for (int u = 0; u < 4; ++u)
                #pragma unroll
                for (int j = 0; j < 4; ++j) {
                    int row = kq * 4 + j;
                    gtl[wave][row][u * 16 + lrow] = acc[u][j]
                        + b2f((unsigned short)p.gp[(size_t)(r0 + row) * 2048 + gn0 + u * 16 + lrow]);
                }
            // LSTM for the 64 gate cols (16 dims) of this group; lane=(row=lrow, base dim=kq)
            #pragma unroll
            for (int pass = 0; pass < 4; ++pass) {
                int row = lrow, dimw = pass * 4 + kq;          // 0..15 within group
                float gi = gtl[wave][row][dimw * 4 + 0];
                float gf = gtl[wave][row][dimw * 4 + 1];
                float gg = gtl[wave][row][dimw * 4 + 2];
                float go = gtl[wave][row][dimw * 4 + 3];
                int d = (gn0 >> 2) + dimw;                     // global dim
                float cv = p.cst[(size_t)(r0 + row) * 512 + d];
                float c2 = sigm(gf) * cv + sigm(gi) * tanh_fast(gg);
                float h2 = sigm(go) * tanh_fast(c2);
                p.cst[(size_t)(r0 + row) * 512 + d] = c2;
                hcl[row][d] = (short)f2b(h2 + c2);
                xehl[row][512 + d] = (short)f2b(h2);
            }
        }
        __syncthreads();
    }

    // ---- q = hc @ WaT + ba (wave covers n = wave*128..+127) ----
    {
        s16x8 afq[16];
        #pragma unroll
        for (int k0 = 0; k0 < 16; ++k0)
            afq[k0] = *(const s16x8*)&hcl[lrow][k0 * 32 + kq * 8];
        for (int ng = 0; ng < 2; ++ng) {
            const int gn0 = wave * 128 + ng * 64;
            f32x4 acc[4] = {};
            #pragma unroll
            for (int k0 = 0; k0 < 16; ++k0) {
                #pragma unroll
                for (int u = 0; u < 4; ++u) {
                    s16x8 bf = *(const s16x8*)(p.WaT + (size_t)(gn0 + u * 16 + lrow) * 512 + k0 * 32 + kq * 8);
                    acc[u] = MFMA_B(afq[k0], bf, acc[u]);
                }
            }
            #pragma unroll
            for (int u = 0; u < 4; ++u)
                #pragma unroll
                for (int j = 0; j < 4; ++j) {
                    int row = kq * 4 + j, col = gn0 + u * 16 + lrow;
                    p.qbf[(size_t)(r0 + row) * 512 + col] = (short)f2b(acc[u][j] + p.ba[col]);
                }
        }
    }

    if (!INIT) {
        // ---- out = log_softmax(h2 @ WoutT + bout), N=128 (wave covers 2 tiles) ----
        {
            s16x8 afh[16];
            #pragma unroll
            for (int k0 = 0; k0 < 16; ++k0)
                afh[k0] = *(const s16x8*)&xehl[lrow][512 + k0 * 32 + kq * 8];
            f32x4 acc[2] = {};
            #pragma unroll
            for (int k0 = 0; k0 < 16; ++k0) {
                #pragma unroll
                for (int u = 0; u < 2; ++u) {
                    s16x8 bf = *(const s16x8*)(p.WoutT + (size_t)(wave * 32 + u * 16 + lrow) * 512 + k0 * 32 + kq * 8);
                    acc[u] = MFMA_B(afh[k0], bf, acc[u]);
                }
            }
            #pragma unroll
            for (int u = 0; u < 2; ++u)
                #pragma unroll
                for (int j = 0; j < 4; ++j) {
                    int col = wave * 32 + u * 16 + lrow;
                    lgl[kq * 4 + j][col] = acc[u][j] + p.bout[col];
                }
        }
        __syncthreads();
        {
            int row = t >> 4, ci = t & 15;
            float v[8]; float mx = -1e30f;
            #pragma unroll
            for (int k = 0; k < 8; ++k) { v[k] = lgl[row][ci * 8 + k]; mx = fmaxf(mx, v[k]); }
            #pragma unroll
            for (int o = 1; o < 16; o <<= 1) mx = fmaxf(mx, __shfl_xor(mx, o));
            float sum = 0.f;
            #pragma unroll
            for (int k = 0; k < 8; ++k) sum += __expf(v[k] - mx);
            #pragma unroll
            for (int o = 1; o < 16; o <<= 1) sum += __shfl_xor(sum, o);
            float lse = mx + __logf(sum);
            float* orow = p.out_logits + ((size_t)(r0 + row) * T_ + step) * V_ + ci * 8;
            #pragma unroll
            for (int k = 0; k < 8; ++k) orow[k] = v[k] - lse;
        }
    }

    // ---- pgate: gp = xeh @ WehT + bcat (wave covers cols wave*512..+511) ----
    {
        s16x8 afx[32];
        #pragma unroll
        for (int k0 = 0; k0 < 32; ++k0)
            afx[k0] = *(const s16x8*)&xehl[lrow][k0 * 32 + kq * 8];
        for (int ng = 0; ng < 8; ++ng) {
            const int gn0 = wave * 512 + ng * 64;
            f32x4 acc[4] = {};
            #pragma unroll
            for (int k0 = 0; k0 < 32; ++k0) {
                #pragma unroll
                for (int u = 0; u < 4; ++u) {
                    s16x8 bf = *(const s16x8*)(p.WehT + (size_t)(gn0 + u * 16 + lrow) * 1024 + k0 * 32 + kq * 8);
                    acc[u] = MFMA_B(afx[k0], bf, acc[u]);
                }
            }
            #pragma unroll
            for (int u = 0; u < 4; ++u)
                #pragma unroll
                for (int j = 0; j < 4; ++j) {
                    int row = kq * 4 + j, col = gn0 + u * 16 + lrow;
                    p.gp[(size_t)(r0 + row) * 2048 + col] = (short)f2b(acc[u][j] + p.bcat[col]);
                }
        }
    }
}

// ---------------- precompute kernels ----------------
__global__ __launch_bounds__(256)
void gemm64(const short* __restrict__ A, const short* __restrict__ Bt,
            const float* __restrict__ bias, short* __restrict__ Cp,
            int M, int N, int K)
{
    __shared__ __align__(16) short As[64][LDW];
    __shared__ __align__(16) short Bs[64][LDW];
    const int t = threadIdx.x;
    const int lane = t & 63, wave = t >> 6;
    const int wr = wave >> 1, wc = wave & 1;
    const int lrow = lane & 15, kq = lane >> 4;
    const int m0 = blockIdx.y * 64, n0 = blockIdx.x * 64;
    const int srow = t >> 3, sseg = t & 7;
    f32x4 acc[2][2] = {};
    for (int k0 = 0; k0 < K; k0 += 64) {
        s16x8 va0 = *(const s16x8*)(A + (size_t)(m0 + srow) * K + k0 + sseg * 8);
        s16x8 va1 = *(const s16x8*)(A + (size_t)(m0 + srow + 32) * K + k0 + sseg * 8);
        s16x8 vb0 = *(const s16x8*)(Bt + (size_t)(n0 + srow) * K + k0 + sseg * 8);
        s16x8 vb1 = *(const s16x8*)(Bt + (size_t)(n0 + srow + 32) * K + k0 + sseg * 8);
        __syncthreads();
        *(s16x8*)(&As[srow][sseg * 8]) = va0;
        *(s16x8*)(&As[srow + 32][sseg * 8]) = va1;
        *(s16x8*)(&Bs[srow][sseg * 8]) = vb0;
        *(s16x8*)(&Bs[srow + 32][sseg * 8]) = vb1;
        __syncthreads();
        for (int kk = 0; kk < 64; kk += 32) {
            s16x8 af[2], bf[2];
            af[0] = *(const s16x8*)(&As[wr * 32 + lrow][kk + kq * 8]);
            af[1] = *(const s16x8*)(&As[wr * 32 + 16 + lrow][kk + kq * 8]);
            bf[0] = *(const s16x8*)(&Bs[wc * 32 + lrow][kk + kq * 8]);
            bf[1] = *(const s16x8*)(&Bs[wc * 32 + 16 + lrow][kk + kq * 8]);
            for (int m2 = 0; m2 < 2; ++m2)
                for (int n2 = 0; n2 < 2; ++n2)
                    acc[m2][n2] = MFMA_B(af[m2], bf[n2], acc[m2][n2]);
        }
    }
    for (int m2 = 0; m2 < 2; ++m2)
        for (int n2 = 0; n2 < 2; ++n2) {
            int col = n0 + wc * 32 + n2 * 16 + lrow;
            float bvv = bias ? bias[col] : 0.0f;
            for (int j = 0; j < 4; ++j) {
                int row = m0 + wr * 32 + m2 * 16 + kq * 4 + j;
                Cp[(size_t)row * N + col] = (short)f2b(acc[m2][n2][j] + bvv);
            }
        }
}

// kpb[b][s][d] (bf16) -> kp8[b][g=d/16][s][16B] (fp8)
__global__ __launch_bounds__(256)
void transpose_kp8(const short* __restrict__ in, unsigned char* __restrict__ out)
{
    const int b = blockIdx.x, t = threadIdx.x;
    const size_t ibase = (size_t)b * (S_ * D_);
    for (int k = t; k < 32 * S_; k += 256) {
        int g = k >> 7, s = k & 127;
        const short* src = in + ibase + (size_t)s * D_ + g * 16;
        unsigned w[4];
        #pragma unroll
        for (int q4 = 0; q4 < 4; ++q4) {
            w[q4] = pk_fp8(b2f((unsigned short)src[q4 * 4 + 0]), b2f((unsigned short)src[q4 * 4 + 1]),
                           b2f((unsigned short)src[q4 * 4 + 2]), b2f((unsigned short)src[q4 * 4 + 3]));
        }
        uint4 o; o.x = w[0]; o.y = w[1]; o.z = w[2]; o.w = w[3];
        *(uint4*)(out + ibase + ((size_t)g * S_ + s) * 16) = o;
    }
}

__global__ __launch_bounds__(256)
void cast_fp8_v4(const float* __restrict__ in, unsigned char* __restrict__ out, int n4)
{
    int i = blockIdx.x * 256 + threadIdx.x;
    int stride = gridDim.x * 256;
    for (; i < n4; i += stride) {
        f32x4 v = ((const f32x4*)in)[i];
        ((unsigned*)out)[i] = pk_fp8(v[0], v[1], v[2], v[3]);
    }
}

__global__ __launch_bounds__(256)
void init_state(const float* __restrict__ e_h, const float* __restrict__ e_c,
                float* __restrict__ c, short* __restrict__ hcbf,
                short* __restrict__ xehg, const float* __restrict__ E)
{
    int gid = blockIdx.x * 256 + threadIdx.x;
    int b = gid >> 9, d = gid & 511;
    float h0 = e_h[gid], c0 = e_c[gid];
    c[gid] = c0;
    hcbf[gid] = (short)f2b(h0 + c0);
    xehg[(size_t)b * 1024 + 512 + d] = (short)f2b(h0);
    xehg[(size_t)b * 1024 + d] = (short)f2b(E[d]);   // token 0 (SOS)
}

__global__ __launch_bounds__(256)
void transpose_cast(const float* __restrict__ in, short* __restrict__ out,
                    int N, int ostride, int koff, int gate_perm)
{
    __shared__ float tile[64][65];
    int t = threadIdx.x;
    int n0 = blockIdx.x * 64, k0 = blockIdx.y * 64;
    int cc = t & 63, r4 = t >> 6;
    for (int i = 0; i < 16; ++i) {
        int r = i * 4 + r4;
        tile[r][cc] = in[(size_t)(k0 + r) * N + n0 + cc];
    }
    __syncthreads();
    for (int i = 0; i < 16; ++i) {
        int nr = i * 4 + r4;
        int ng = n0 + nr;
        int np = gate_perm ? ((ng & 511) * 4 + (ng >> 9)) : ng;
        out[(size_t)np * ostride + koff + k0 + cc] = (short)f2b(tile[cc][nr]);
    }
}

__global__ __launch_bounds__(256)
void cast_bf16_v4(const float* __restrict__ in, short* __restrict__ out, int n4)
{
    int i = blockIdx.x * 256 + threadIdx.x;
    int stride = gridDim.x * 256;
    for (; i < n4; i += stride) {
        f32x4 v = ((const f32x4*)in)[i];
        s16x4 o;
        for (int j = 0; j < 4; ++j) o[j] = (short)f2b(v[j]);
        ((s16x4*)out)[i] = o;
    }
}

__global__ __launch_bounds__(256)
void make_bcat(const float* __restrict__ b_ih, const float* __restrict__ b_hh, float* __restrict__ bcat)
{
    int i = blockIdx.x * 256 + threadIdx.x;
    if (i < 2048) {
        int np = (i & 511) * 4 + (i >> 9);
        bcat[np] = b_ih[i] + b_hh[i];
    }
}

extern "C" void kernel_launch(void* const* d_in, const int* in_sizes, int n_in,
                              void* d_out, int out_size, void* d_ws, size_t ws_size,
                              hipStream_t stream)
{
    const float* e_all  = (const float*)d_in[0];
    const float* e_h    = (const float*)d_in[1];
    const float* e_c    = (const float*)d_in[2];
    const int*   target = (const int*)d_in[3];
    const float* E      = (const float*)d_in[4];
    const float* Wa     = (const float*)d_in[5];
    const float* ba     = (const float*)d_in[6];
    const float* Ua     = (const float*)d_in[7];
    const float* bu     = (const float*)d_in[8];
    const float* Va     = (const float*)d_in[9];
    const float* bv     = (const float*)d_in[10];
    const float* W_ih   = (const float*)d_in[11];
    const float* b_ih   = (const float*)d_in[12];
    const float* W_hh   = (const float*)d_in[13];
    const float* b_hh   = (const float*)d_in[14];
    const float* W_out  = (const float*)d_in[15];
    const float* b_out  = (const float*)d_in[16];

    char* ws = (char*)d_ws;
    size_t off = 0;
    auto alloc = [&](size_t bytes) { void* p = ws + off; off += (bytes + 255) & ~255ull; return p; };
    short* ealb  = (short*)alloc((size_t)B_ * S_ * D_ * 2);
    short* kpb   = (short*)alloc((size_t)B_ * S_ * D_ * 2);
    unsigned char* kp8 = (unsigned char*)alloc((size_t)B_ * S_ * D_);
    unsigned char* ea8 = (unsigned char*)alloc((size_t)B_ * S_ * D_);
    short* WaT   = (short*)alloc((size_t)D_ * D_ * 2);
    short* UaT   = (short*)alloc((size_t)D_ * D_ * 2);
    short* WehT  = (short*)alloc((size_t)2048 * 1024 * 2);
    short* WctxT = (short*)alloc((size_t)2048 * 512 * 2);
    short* WoutT = (short*)alloc((size_t)V_ * D_ * 2);
    float* bcat  = (float*)alloc(2048 * 4);
    short* qbf   = (short*)alloc((size_t)B_ * D_ * 2);
    short* vab   = (short*)alloc((size_t)D_ * 2);
    short* xehg  = (short*)alloc((size_t)B_ * 1024 * 2);
    short* ctxb  = (short*)alloc((size_t)B_ * D_ * 2);
    short* gp    = (short*)alloc((size_t)B_ * 2048 * 2);
    short* hcbf  = (short*)alloc((size_t)B_ * D_ * 2);
    float* cst   = (float*)alloc((size_t)B_ * D_ * 4);
    if (off > ws_size) return;

    float* out_logits = (float*)d_out;                        // [B,T,V]
    float* out_attn   = (float*)d_out + (size_t)B_ * T_ * V_; // [B,T,S]

    // ---- precompute ----
    cast_bf16_v4<<<4096, 256, 0, stream>>>(e_all, ealb, B_ * S_ * D_ / 4);
    cast_fp8_v4<<<4096, 256, 0, stream>>>(e_all, ea8, B_ * S_ * D_ / 4);
    cast_bf16_v4<<<1,    256, 0, stream>>>(Va, vab, D_ / 4);
    transpose_cast<<<dim3(8, 8),  256, 0, stream>>>(Wa,  WaT,  512,  512, 0, 0);
    transpose_cast<<<dim3(8, 8),  256, 0, stream>>>(Ua,  UaT,  512,  512, 0, 0);
    transpose_cast<<<dim3(32, 16), 256, 0, stream>>>(W_ih, WehT, 2048, 1024, 0, 1);
    transpose_cast<<<dim3(32, 8), 256, 0, stream>>>(W_ih + 512 * 2048, WctxT, 2048, 512, 0, 1);
    transpose_cast<<<dim3(32, 8), 256, 0, stream>>>(W_hh, WehT, 2048, 1024, 512, 1);
    transpose_cast<<<dim3(2, 8),  256, 0, stream>>>(W_out, WoutT, 128, 512, 0, 0);
    make_bcat<<<8, 256, 0, stream>>>(b_ih, b_hh, bcat);
    gemm64<<<dim3(8, 1024), 256, 0, stream>>>(ealb, UaT, bu, kpb, B_ * S_, 512, 512);
    transpose_kp8<<<512, 256, 0, stream>>>(kpb, kp8);
    init_state<<<1024, 256, 0, stream>>>(e_h, e_c, cst, hcbf, xehg, E);

    P pp;
    pp.target = target; pp.E = E; pp.bv = bv; pp.ba = ba; pp.bout = b_out; pp.bcat = bcat;
    pp.vab = vab; pp.ea8 = ea8; pp.kp8 = kp8;
    pp.WaT = WaT; pp.WehT = WehT; pp.WctxT = WctxT; pp.WoutT = WoutT;
    pp.qbf = qbf; pp.ctxb = ctxb; pp.gp = gp;
    pp.cst = cst; pp.hcbf = hcbf; pp.xehg = xehg;
    pp.out_logits = out_logits; pp.out_attn = out_attn;

    // q(0) + gp(0) from initial state (row-local, reads hcbf/xehg)
    kE<true><<<32, 256, 0, stream>>>(pp, 0);

    // ---- sequential decode: 2 dispatches per step ----
    for (int t = 0; t < T_; ++t) {
        kA<<<512, 256, 0, stream>>>(pp, t);
        kE<false><<<32, 256, 0, stream>>>(pp, t);
    }
    (void)n_in; (void)in_sizes; (void)out_size;
}

// Round 12
// 15065.408 us; speedup vs baseline: 2.0036x; 2.0036x over previous
//
#include <hip/hip_runtime.h>

#define B_ 512
#define S_ 128
#define T_ 128
#define D_ 512
#define V_ 128
#define LDW 72

typedef __attribute__((ext_vector_type(8))) short s16x8;
typedef __attribute__((ext_vector_type(4))) short s16x4;
typedef __attribute__((ext_vector_type(4))) float f32x4;

__device__ __forceinline__ float b2f(unsigned short h) {
    union { unsigned int u; float f; } x; x.u = ((unsigned int)h) << 16; return x.f;
}
__device__ __forceinline__ unsigned short f2b(float f) {
    union { float f; unsigned int u; } x; x.f = f;
    unsigned int u = x.u; u += 0x7FFFu + ((u >> 16) & 1u);
    return (unsigned short)(u >> 16);
}
#if __has_builtin(__builtin_amdgcn_rcpf)
__device__ __forceinline__ float rcp_f(float x) { return __builtin_amdgcn_rcpf(x); }
#else
__device__ __forceinline__ float rcp_f(float x) { return 1.0f / x; }
#endif
__device__ __forceinline__ float sigm(float x) { return rcp_f(1.0f + __expf(-x)); }
__device__ __forceinline__ float tanh_fast(float x) {
    float e = __expf(2.0f * fabsf(x));
    float r = 1.0f - 2.0f * rcp_f(e + 1.0f);
    return copysignf(r, x);
}
__device__ __forceinline__ float tanh_pade(float x) {
    float t = x * x;
    float num = x * fmaf(t, 105.0f + t, 945.0f);
    float den = fmaf(t, fmaf(t, 15.0f, 420.0f), 945.0f);
    float r = num * rcp_f(den);
    return fminf(1.0f, fmaxf(-1.0f, r));
}

#if __has_builtin(__builtin_amdgcn_cvt_f32_fp8)
__device__ __forceinline__ f32x4 fp8x4_dec(unsigned w) {
    f32x4 r;
    r[0] = __builtin_amdgcn_cvt_f32_fp8(w, 0);
    r[1] = __builtin_amdgcn_cvt_f32_fp8(w, 1);
    r[2] = __builtin_amdgcn_cvt_f32_fp8(w, 2);
    r[3] = __builtin_amdgcn_cvt_f32_fp8(w, 3);
    return r;
}
#else
__device__ __forceinline__ float fp8_dec_sw(unsigned w, int j) {
    unsigned char v = (w >> (8 * j)) & 0xFF;
    unsigned s = v >> 7, e = (v >> 3) & 0xF, m = v & 7;
    float r = (e == 0) ? ldexpf((float)m, -9) : ldexpf((float)(8 + m), (int)e - 10);
    return s ? -r : r;
}
__device__ __forceinline__ f32x4 fp8x4_dec(unsigned w) {
    f32x4 r;
    r[0] = fp8_dec_sw(w, 0); r[1] = fp8_dec_sw(w, 1);
    r[2] = fp8_dec_sw(w, 2); r[3] = fp8_dec_sw(w, 3);
    return r;
}
#endif

#if __has_builtin(__builtin_amdgcn_cvt_pk_fp8_f32)
__device__ __forceinline__ unsigned pk_fp8(float a, float b, float c, float d) {
    int r = 0;
    r = __builtin_amdgcn_cvt_pk_fp8_f32(a, b, r, false);
    r = __builtin_amdgcn_cvt_pk_fp8_f32(c, d, r, true);
    return (unsigned)r;
}
#else
__device__ __forceinline__ unsigned char f32_to_fp8_sw(float x) {
    unsigned s = x < 0.f ? 0x80u : 0u; float a = fabsf(x);
    if (a != a) return (unsigned char)(s | 0x7F);
    if (a >= 448.f) return (unsigned char)(s | 0x7E);
    if (a < 0.001953125f) { int m = (int)rintf(a * 512.0f); return (unsigned char)(s | (m > 7 ? 0x08 : m)); }
    int e; float fr = frexpf(a, &e);
    int m = (int)rintf(fr * 16.0f - 8.0f);
    int ee = e - 1 + 7;
    if (m == 8) { m = 0; ee += 1; }
    if (ee <= 0) { int mm = (int)rintf(a * 512.f); return (unsigned char)(s | (mm > 7 ? 0x08 : mm)); }
    if (ee >= 16) return (unsigned char)(s | 0x7E);
    return (unsigned char)(s | (ee << 3) | m);
}
__device__ __forceinline__ unsigned pk_fp8(float a, float b, float c, float d) {
    return (unsigned)f32_to_fp8_sw(a) | ((unsigned)f32_to_fp8_sw(b) << 8)
         | ((unsigned)f32_to_fp8_sw(c) << 16) | ((unsigned)f32_to_fp8_sw(d) << 24);
}
#endif

struct P {
    const int* target;
    const float* E; const float* bv; const float* ba; const float* bout; const float* bcat;
    const short* vab;
    const unsigned char* ea8; const unsigned char* kp8;
    const short* WaT; const short* WehT; const short* WctxT; const short* WoutT;
    short* qbf; short* ctxb; short* gp0; short* gp1;
    float* cst; short* hcbf; short* h2bf; short* xeh;
    unsigned* flags;
    float* out_logits; float* out_attn;
};

struct GateS { short As[64][LDW]; short Bs[64][LDW]; float gt[64][65]; };
struct PG2   { short As[128][LDW]; short Bs[64][LDW]; };
struct OutS  { short As[64][LDW]; short Bs[128][LDW]; };
union SharedBC { GateS g; PG2 pg; OutS o; };

// ---------------- flag sync (agent scope; per 64-row group; 32 producers each) ----------------
__device__ __forceinline__ void signal_flag(unsigned* f) {
    __syncthreads();                 // all waves' stores drained to L2
    __threadfence();                 // agent release: L2 writeback
    if (threadIdx.x == 0)
        __hip_atomic_fetch_add(f, 1u, __ATOMIC_RELAXED, __HIP_MEMORY_SCOPE_AGENT);
}
__device__ __forceinline__ void wait_flag(unsigned* f, unsigned tgt) {
    if (threadIdx.x == 0) {
        while (__hip_atomic_load(f, __ATOMIC_RELAXED, __HIP_MEMORY_SCOPE_AGENT) < tgt)
            __builtin_amdgcn_s_sleep(2);
    }
    __syncthreads();
    __threadfence();                 // agent acquire: invalidate stale L1/L2
}

// ================= kA: attention, 512 blocks (1 row each) =================
__global__ __launch_bounds__(256, 2) void kA(P p, int step)
{
    __shared__ float scp[4][64];
    __shared__ float wbuf[S_];
    __shared__ float cpart[4][D_];
    const int b = blockIdx.x;
    const int t = threadIdx.x, lane = t & 63, wave = t >> 6;
    {
        const int sg = wave & 1, dh = wave >> 1;
        const int s = sg * 64 + lane;
        const unsigned char* kb = p.kp8 + (size_t)b * (S_ * D_);
        const short* qv = p.qbf + (size_t)b * D_;
        float acc = 0.f;
        #pragma unroll 4
        for (int i = 0; i < 16; ++i) {
            int g = dh * 16 + i;
            uint4 kw = *(const uint4*)(kb + ((size_t)g * 128 + s) * 16);
            const short* qg = qv + g * 16;
            const short* vg = p.vab + g * 16;
            s16x8 q0 = *(const s16x8*)(qg), q1 = *(const s16x8*)(qg + 8);
            s16x8 v0 = *(const s16x8*)(vg), v1 = *(const s16x8*)(vg + 8);
            f32x4 ka = fp8x4_dec(kw.x), kb4 = fp8x4_dec(kw.y);
            f32x4 kc = fp8x4_dec(kw.z), kd = fp8x4_dec(kw.w);
            #pragma unroll
            for (int j = 0; j < 4; ++j) {
                acc += tanh_pade(b2f((unsigned short)q0[j])     + ka[j])  * b2f((unsigned short)v0[j]);
                acc += tanh_pade(b2f((unsigned short)q0[4 + j]) + kb4[j]) * b2f((unsigned short)v0[4 + j]);
                acc += tanh_pade(b2f((unsigned short)q1[j])     + kc[j])  * b2f((unsigned short)v1[j]);
                acc += tanh_pade(b2f((unsigned short)q1[4 + j]) + kd[j])  * b2f((unsigned short)v1[4 + j]);
            }
        }
        scp[wave][lane] = acc;
    }
    __syncthreads();
    if (wave == 0) {
        const float bvv = p.bv[0];
        float v0 = scp[0][lane] + scp[2][lane] + bvv;
        float v1 = scp[1][lane] + scp[3][lane] + bvv;
        float m = fmaxf(v0, v1);
        #pragma unroll
        for (int o = 32; o >= 1; o >>= 1) m = fmaxf(m, __shfl_xor(m, o));
        float e0 = __expf(v0 - m), e1 = __expf(v1 - m);
        float su = e0 + e1;
        #pragma unroll
        for (int o = 32; o >= 1; o >>= 1) su += __shfl_xor(su, o);
        float inv = rcp_f(su);
        float w0 = e0 * inv, w1 = e1 * inv;
        wbuf[lane] = w0; wbuf[lane + 64] = w1;
        float* ao = p.out_attn + ((size_t)b * T_ + step) * S_;
        ao[lane] = w0; ao[lane + 64] = w1;
    }
    __syncthreads();
    {
        const int d0 = lane * 8;
        f32x4 aA = {0.f,0.f,0.f,0.f}, aB = {0.f,0.f,0.f,0.f};
        const unsigned char* eb = p.ea8 + (size_t)b * S_ * D_ + d0;
        #pragma unroll 4
        for (int i = 0; i < 32; ++i) {
            int s = wave * 32 + i;
            float wv = wbuf[s];
            uint2 ev = *(const uint2*)(eb + (size_t)s * D_);
            f32x4 ex = fp8x4_dec(ev.x), ey = fp8x4_dec(ev.y);
            #pragma unroll
            for (int j = 0; j < 4; ++j) aA[j] += wv * ex[j];
            #pragma unroll
            for (int j = 0; j < 4; ++j) aB[j] += wv * ey[j];
        }
        *(f32x4*)&cpart[wave][d0]     = aA;
        *(f32x4*)&cpart[wave][d0 + 4] = aB;
    }
    __syncthreads();
    {
        int dd = t * 2;
        float v0 = cpart[0][dd]   + cpart[1][dd]   + cpart[2][dd]   + cpart[3][dd];
        float v1 = cpart[0][dd+1] + cpart[1][dd+1] + cpart[2][dd+1] + cpart[3][dd+1];
        short2 o2; o2.x = (short)f2b(v0); o2.y = (short)f2b(v1);
        *(short2*)(p.ctxb + (size_t)b * D_ + dd) = o2;
    }
}

// ---------------- fgate (64x64 tile, K=512 ctx) + gp(read) + fused LSTM ----------------
__device__ __forceinline__ void fgate_phase(const P& p, GateS& sh, int bid, int step,
                                            const short* __restrict__ gprd)
{
    const int t = threadIdx.x, lane = t & 63, wave = t >> 6;
    const int wr = wave >> 1, wc = wave & 1;
    const int lrow = lane & 15, kq = lane >> 4;
    const int srow = t >> 3, sseg = t & 7;
    const int m0 = (bid >> 5) * 64, n0 = (bid & 31) * 64;
    f32x4 acc[2][2] = {};
    for (int k0 = 0; k0 < 512; k0 += 64) {
        s16x8 va0 = *(const s16x8*)(p.ctxb + (size_t)(m0 + srow) * 512 + k0 + sseg * 8);
        s16x8 va1 = *(const s16x8*)(p.ctxb + (size_t)(m0 + srow + 32) * 512 + k0 + sseg * 8);
        s16x8 vb0 = *(const s16x8*)(p.WctxT + (size_t)(n0 + srow) * 512 + k0 + sseg * 8);
        s16x8 vb1 = *(const s16x8*)(p.WctxT + (size_t)(n0 + srow + 32) * 512 + k0 + sseg * 8);
        __syncthreads();
        *(s16x8*)(&sh.As[srow][sseg * 8]) = va0;
        *(s16x8*)(&sh.As[srow + 32][sseg * 8]) = va1;
        *(s16x8*)(&sh.Bs[srow][sseg * 8]) = vb0;
        *(s16x8*)(&sh.Bs[srow + 32][sseg * 8]) = vb1;
        __syncthreads();
        #pragma unroll
        for (int kk = 0; kk < 64; kk += 32) {
            s16x8 af0 = *(const s16x8*)(&sh.As[wr * 32 + lrow][kk + kq * 8]);
            s16x8 af1 = *(const s16x8*)(&sh.As[wr * 32 + 16 + lrow][kk + kq * 8]);
            s16x8 bf0 = *(const s16x8*)(&sh.Bs[wc * 32 + lrow][kk + kq * 8]);
            s16x8 bf1 = *(const s16x8*)(&sh.Bs[wc * 32 + 16 + lrow][kk + kq * 8]);
            acc[0][0] = __builtin_amdgcn_mfma_f32_16x16x32_bf16(af0, bf0, acc[0][0], 0, 0, 0);
            acc[0][1] = __builtin_amdgcn_mfma_f32_16x16x32_bf16(af0, bf1, acc[0][1], 0, 0, 0);
            acc[1][0] = __builtin_amdgcn_mfma_f32_16x16x32_bf16(af1, bf0, acc[1][0], 0, 0, 0);
            acc[1][1] = __builtin_amdgcn_mfma_f32_16x16x32_bf16(af1, bf1, acc[1][1], 0, 0, 0);
        }
    }
    #pragma unroll
    for (int m2 = 0; m2 < 2; ++m2)
        #pragma unroll
        for (int n2 = 0; n2 < 2; ++n2) {
            int cl = wc * 32 + n2 * 16 + lrow;
            #pragma unroll
            for (int j = 0; j < 4; ++j) {
                int rl = wr * 32 + m2 * 16 + kq * 4 + j;
                sh.gt[rl][cl] = acc[m2][n2][j]
                              + b2f((unsigned short)gprd[(size_t)(m0 + rl) * 2048 + n0 + cl]);
            }
        }
    __syncthreads();
    const int rl4 = t >> 4, dl = t & 15;
    #pragma unroll
    for (int pass = 0; pass < 4; ++pass) {
        int row = pass * 16 + rl4;
        int b = m0 + row;
        int d = (n0 >> 2) + dl;
        float gi = sh.gt[row][dl * 4 + 0];
        float gf = sh.gt[row][dl * 4 + 1];
        float gg = sh.gt[row][dl * 4 + 2];
        float go = sh.gt[row][dl * 4 + 3];
        float cv = p.cst[(size_t)b * D_ + d];
        float c2 = sigm(gf) * cv + sigm(gi) * tanh_fast(gg);
        float h2 = sigm(go) * tanh_fast(c2);
        p.cst[(size_t)b * D_ + d] = c2;
        p.hcbf[(size_t)b * D_ + d] = (short)f2b(h2 + c2);
        p.h2bf[(size_t)b * D_ + d] = (short)f2b(h2);
        p.xeh[(size_t)b * 1024 + 512 + d] = (short)f2b(h2);
        int tok = p.target[b * T_ + step];
        p.xeh[(size_t)b * 1024 + d] = (short)f2b(p.E[(size_t)tok * D_ + d]);
    }
}

// ---------------- q GEMM 64x64 (M=N=K=512) -> bf16 q ----------------
__device__ __forceinline__ void q64_phase(const P& p, OutS& sh, int bid)
{
    const int t = threadIdx.x, lane = t & 63, wave = t >> 6;
    const int wr = wave >> 1, wc = wave & 1;
    const int lrow = lane & 15, kq = lane >> 4;
    const int srow = t >> 3, sseg = t & 7;
    const int m0 = (bid >> 3) * 64, n0 = (bid & 7) * 64;
    f32x4 acc[2][2] = {};
    for (int k0 = 0; k0 < 512; k0 += 64) {
        s16x8 va0 = *(const s16x8*)(p.hcbf + (size_t)(m0 + srow) * 512 + k0 + sseg * 8);
        s16x8 va1 = *(const s16x8*)(p.hcbf + (size_t)(m0 + srow + 32) * 512 + k0 + sseg * 8);
        s16x8 vb0 = *(const s16x8*)(p.WaT + (size_t)(n0 + srow) * 512 + k0 + sseg * 8);
        s16x8 vb1 = *(const s16x8*)(p.WaT + (size_t)(n0 + srow + 32) * 512 + k0 + sseg * 8);
        __syncthreads();
        *(s16x8*)(&sh.As[srow][sseg * 8]) = va0;
        *(s16x8*)(&sh.As[srow + 32][sseg * 8]) = va1;
        *(s16x8*)(&sh.Bs[srow][sseg * 8]) = vb0;
        *(s16x8*)(&sh.Bs[srow + 32][sseg * 8]) = vb1;
        __syncthreads();
        #pragma unroll
        for (int kk = 0; kk < 64; kk += 32) {
            s16x8 af0 = *(const s16x8*)(&sh.As[wr * 32 + lrow][kk + kq * 8]);
            s16x8 af1 = *(const s16x8*)(&sh.As[wr * 32 + 16 + lrow][kk + kq * 8]);
            s16x8 bf0 = *(const s16x8*)(&sh.Bs[wc * 32 + lrow][kk + kq * 8]);
            s16x8 bf1 = *(const s16x8*)(&sh.Bs[wc * 32 + 16 + lrow][kk + kq * 8]);
            acc[0][0] = __builtin_amdgcn_mfma_f32_16x16x32_bf16(af0, bf0, acc[0][0], 0, 0, 0);
            acc[0][1] = __builtin_amdgcn_mfma_f32_16x16x32_bf16(af0, bf1, acc[0][1], 0, 0, 0);
            acc[1][0] = __builtin_amdgcn_mfma_f32_16x16x32_bf16(af1, bf0, acc[1][0], 0, 0, 0);
            acc[1][1] = __builtin_amdgcn_mfma_f32_16x16x32_bf16(af1, bf1, acc[1][1], 0, 0, 0);
        }
    }
    #pragma unroll
    for (int m2 = 0; m2 < 2; ++m2)
        #pragma unroll
        for (int n2 = 0; n2 < 2; ++n2) {
            int col = n0 + wc * 32 + n2 * 16 + lrow;
            float bvv = p.ba[col];
            #pragma unroll
            for (int j = 0; j < 4; ++j) {
                int row = m0 + wr * 32 + m2 * 16 + kq * 4 + j;
                p.qbf[(size_t)row * 512 + col] = (short)f2b(acc[m2][n2][j] + bvv);
            }
        }
}

// ---------------- pgate full-K (128x64 tile, K=1024): gp = xeh @ WehT^T + bcat -> bf16 ------------
__device__ __forceinline__ void pgate_full(const P& p, PG2& sh, int bid2, short* __restrict__ gpw)
{
    const int t = threadIdx.x, lane = t & 63, wave = t >> 6;
    const int lrow = lane & 15, kq = lane >> 4;
    const int m0 = (bid2 >> 5) * 128, n0 = (bid2 & 31) * 64;
    f32x4 acc[2][4] = {};
    for (int k0 = 0; k0 < 1024; k0 += 64) {
        s16x8 va[4], vb[2];
        #pragma unroll
        for (int r = 0; r < 4; ++r) {
            int idx = r * 256 + t, row = idx >> 3, seg = idx & 7;
            va[r] = *(const s16x8*)(p.xeh + (size_t)(m0 + row) * 1024 + k0 + seg * 8);
        }
        #pragma unroll
        for (int r = 0; r < 2; ++r) {
            int idx = r * 256 + t, row = idx >> 3, seg = idx & 7;
            vb[r] = *(const s16x8*)(p.WehT + (size_t)(n0 + row) * 1024 + k0 + seg * 8);
        }
        __syncthreads();
        #pragma unroll
        for (int r = 0; r < 4; ++r) {
            int idx = r * 256 + t, row = idx >> 3, seg = idx & 7;
            *(s16x8*)(&sh.As[row][seg * 8]) = va[r];
        }
        #pragma unroll
        for (int r = 0; r < 2; ++r) {
            int idx = r * 256 + t, row = idx >> 3, seg = idx & 7;
            *(s16x8*)(&sh.Bs[row][seg * 8]) = vb[r];
        }
        __syncthreads();
        #pragma unroll
        for (int kk = 0; kk < 64; kk += 32) {
            s16x8 af[2], bf[4];
            af[0] = *(const s16x8*)(&sh.As[wave * 32 + lrow][kk + kq * 8]);
            af[1] = *(const s16x8*)(&sh.As[wave * 32 + 16 + lrow][kk + kq * 8]);
            #pragma unroll
            for (int f = 0; f < 4; ++f)
                bf[f] = *(const s16x8*)(&sh.Bs[f * 16 + lrow][kk + kq * 8]);
            #pragma unroll
            for (int m2 = 0; m2 < 2; ++m2)
                #pragma unroll
                for (int n2 = 0; n2 < 4; ++n2)
                    acc[m2][n2] = __builtin_amdgcn_mfma_f32_16x16x32_bf16(af[m2], bf[n2], acc[m2][n2], 0, 0, 0);
        }
    }
    #pragma unroll
    for (int m2 = 0; m2 < 2; ++m2)
        #pragma unroll
        for (int n2 = 0; n2 < 4; ++n2) {
            int col = n0 + n2 * 16 + lrow;
            float bvv = p.bcat[col];
            #pragma unroll
            for (int j = 0; j < 4; ++j) {
                int row = m0 + wave * 32 + m2 * 16 + kq * 4 + j;
                gpw[(size_t)row * 2048 + col] = (short)f2b(acc[m2][n2][j] + bvv);
            }
        }
}

// ---------------- out GEMM (64 rows, N=128, K=512) + fused log_softmax ----------------
__device__ __forceinline__ void out_phase(const P& p, OutS& sh, int obid, int step)
{
    const int t = threadIdx.x, lane = t & 63, wave = t >> 6;
    const int lrow = lane & 15, kq = lane >> 4;
    const int srow = t >> 3, sseg = t & 7;
    const int m0 = obid * 64;
    f32x4 acc[8] = {};
    for (int k0 = 0; k0 < 512; k0 += 64) {
        s16x8 va0 = *(const s16x8*)(p.h2bf + (size_t)(m0 + srow) * 512 + k0 + sseg * 8);
        s16x8 va1 = *(const s16x8*)(p.h2bf + (size_t)(m0 + srow + 32) * 512 + k0 + sseg * 8);
        s16x8 vb[4];
        #pragma unroll
        for (int p4 = 0; p4 < 4; ++p4)
            vb[p4] = *(const s16x8*)(p.WoutT + (size_t)(srow + p4 * 32) * 512 + k0 + sseg * 8);
        __syncthreads();
        *(s16x8*)(&sh.As[srow][sseg * 8]) = va0;
        *(s16x8*)(&sh.As[srow + 32][sseg * 8]) = va1;
        #pragma unroll
        for (int p4 = 0; p4 < 4; ++p4) *(s16x8*)(&sh.Bs[srow + p4 * 32][sseg * 8]) = vb[p4];
        __syncthreads();
        #pragma unroll
        for (int kk = 0; kk < 64; kk += 32) {
            s16x8 a = *(const s16x8*)(&sh.As[wave * 16 + lrow][kk + kq * 8]);
            #pragma unroll
            for (int f = 0; f < 8; ++f) {
                s16x8 b = *(const s16x8*)(&sh.Bs[f * 16 + lrow][kk + kq * 8]);
                acc[f] = __builtin_amdgcn_mfma_f32_16x16x32_bf16(a, b, acc[f], 0, 0, 0);
            }
        }
    }
    float colb[8];
    #pragma unroll
    for (int f = 0; f < 8; ++f) colb[f] = p.bout[f * 16 + lrow];
    #pragma unroll
    for (int j = 0; j < 4; ++j) {
        float v[8]; float mx = -1e30f;
        #pragma unroll
        for (int f = 0; f < 8; ++f) { v[f] = acc[f][j] + colb[f]; mx = fmaxf(mx, v[f]); }
        #pragma unroll
        for (int o = 1; o < 16; o <<= 1) mx = fmaxf(mx, __shfl_xor(mx, o));
        float sum = 0.f;
        #pragma unroll
        for (int f = 0; f < 8; ++f) sum += __expf(v[f] - mx);
        #pragma unroll
        for (int o = 1; o < 16; o <<= 1) sum += __shfl_xor(sum, o);
        float lse = mx + __logf(sum);
        int row = m0 + wave * 16 + kq * 4 + j;
        float* orow = p.out_logits + ((size_t)row * T_ + step) * V_;
        #pragma unroll
        for (int f = 0; f < 8; ++f) orow[f * 16 + lrow] = v[f] - lse;
    }
}

// ===== kBC: fgate(0..255, producers) | q(256..319) | pgate(320..447) | out(448..455) =====
// 456 blocks <= 512 resident slots (2/CU) -> all co-resident, spin-wait is deadlock-free.
__global__ __launch_bounds__(256, 2) void kBC(P p, int step)
{
    __shared__ SharedBC sh;
    const int bid = blockIdx.x;
    unsigned* fl = p.flags + step * 8;
    short* gprd = (step & 1) ? p.gp1 : p.gp0;
    short* gpwr = (step & 1) ? p.gp0 : p.gp1;
    if (bid < 256) {
        fgate_phase(p, sh.g, bid, step, gprd);
        signal_flag(&fl[bid >> 5]);
    } else if (bid < 320) {
        int qb = bid - 256;
        wait_flag(&fl[qb >> 3], 32);
        q64_phase(p, sh.o, qb);
    } else if (bid < 448) {
        int pb = bid - 320;
        int mg = (pb >> 5) * 2;
        wait_flag(&fl[mg], 32);
        wait_flag(&fl[mg + 1], 32);
        pgate_full(p, sh.pg, pb, gpwr);
    } else {
        int ob = bid - 448;
        wait_flag(&fl[ob], 32);
        out_phase(p, sh.o, ob, step);
    }
}

// kInit: q(0..63) + pgate(64..191) from initial state, no waits; writes gp0 (step 0 parity)
__global__ __launch_bounds__(256, 2) void kInit(P p)
{
    __shared__ SharedBC sh;
    const int bid = blockIdx.x;
    if (bid < 64) q64_phase(p, sh.o, bid);
    else          pgate_full(p, sh.pg, bid - 64, p.gp0);
}

__global__ __launch_bounds__(256) void zero_flags(unsigned* f, int n)
{
    int i = blockIdx.x * 256 + threadIdx.x;
    if (i < n) f[i] = 0;
}

// ---------------- precompute kernels ----------------
__global__ __launch_bounds__(256)
void gemm64(const short* __restrict__ A, const short* __restrict__ Bt,
            const float* __restrict__ bias, short* __restrict__ Cp,
            int M, int N, int K)
{
    __shared__ __align__(16) short As[64][LDW];
    __shared__ __align__(16) short Bs[64][LDW];
    const int t = threadIdx.x;
    const int lane = t & 63, wave = t >> 6;
    const int wr = wave >> 1, wc = wave & 1;
    const int lrow = lane & 15, kq = lane >> 4;
    const int m0 = blockIdx.y * 64, n0 = blockIdx.x * 64;
    const int srow = t >> 3, sseg = t & 7;
    f32x4 acc[2][2] = {};
    for (int k0 = 0; k0 < K; k0 += 64) {
        s16x8 va0 = *(const s16x8*)(A + (size_t)(m0 + srow) * K + k0 + sseg * 8);
        s16x8 va1 = *(const s16x8*)(A + (size_t)(m0 + srow + 32) * K + k0 + sseg * 8);
        s16x8 vb0 = *(const s16x8*)(Bt + (size_t)(n0 + srow) * K + k0 + sseg * 8);
        s16x8 vb1 = *(const s16x8*)(Bt + (size_t)(n0 + srow + 32) * K + k0 + sseg * 8);
        __syncthreads();
        *(s16x8*)(&As[srow][sseg * 8]) = va0;
        *(s16x8*)(&As[srow + 32][sseg * 8]) = va1;
        *(s16x8*)(&Bs[srow][sseg * 8]) = vb0;
        *(s16x8*)(&Bs[srow + 32][sseg * 8]) = vb1;
        __syncthreads();
        for (int kk = 0; kk < 64; kk += 32) {
            s16x8 af[2], bf[2];
            af[0] = *(const s16x8*)(&As[wr * 32 + lrow][kk + kq * 8]);
            af[1] = *(const s16x8*)(&As[wr * 32 + 16 + lrow][kk + kq * 8]);
            bf[0] = *(const s16x8*)(&Bs[wc * 32 + lrow][kk + kq * 8]);
            bf[1] = *(const s16x8*)(&Bs[wc * 32 + 16 + lrow][kk + kq * 8]);
            for (int m2 = 0; m2 < 2; ++m2)
                for (int n2 = 0; n2 < 2; ++n2)
                    acc[m2][n2] = __builtin_amdgcn_mfma_f32_16x16x32_bf16(af[m2], bf[n2], acc[m2][n2], 0, 0, 0);
        }
    }
    for (int m2 = 0; m2 < 2; ++m2)
        for (int n2 = 0; n2 < 2; ++n2) {
            int col = n0 + wc * 32 + n2 * 16 + lrow;
            float bvv = bias ? bias[col] : 0.0f;
            for (int j = 0; j < 4; ++j) {
                int row = m0 + wr * 32 + m2 * 16 + kq * 4 + j;
                Cp[(size_t)row * N + col] = (short)f2b(acc[m2][n2][j] + bvv);
            }
        }
}

// kpb[b][s][d] (bf16) -> kp8[b][g=d/16][s][16B] (fp8)
__global__ __launch_bounds__(256)
void transpose_kp8(const short* __restrict__ in, unsigned char* __restrict__ out)
{
    const int b = blockIdx.x, t = threadIdx.x;
    const size_t ibase = (size_t)b * (S_ * D_);
    for (int k = t; k < 32 * S_; k += 256) {
        int g = k >> 7, s = k & 127;
        const short* src = in + ibase + (size_t)s * D_ + g * 16;
        unsigned w[4];
        #pragma unroll
        for (int q4 = 0; q4 < 4; ++q4) {
            w[q4] = pk_fp8(b2f((unsigned short)src[q4 * 4 + 0]), b2f((unsigned short)src[q4 * 4 + 1]),
                           b2f((unsigned short)src[q4 * 4 + 2]), b2f((unsigned short)src[q4 * 4 + 3]));
        }
        uint4 o; o.x = w[0]; o.y = w[1]; o.z = w[2]; o.w = w[3];
        *(uint4*)(out + ibase + ((size_t)g * S_ + s) * 16) = o;
    }
}

__global__ __launch_bounds__(256)
void cast_fp8_v4(const float* __restrict__ in, unsigned char* __restrict__ out, int n4)
{
    int i = blockIdx.x * 256 + threadIdx.x;
    int stride = gridDim.x * 256;
    for (; i < n4; i += stride) {
        f32x4 v = ((const f32x4*)in)[i];
        ((unsigned*)out)[i] = pk_fp8(v[0], v[1], v[2], v[3]);
    }
}

__global__ __launch_bounds__(256)
void init_state(const float* __restrict__ e_h, const float* __restrict__ e_c,
                float* __restrict__ c, short* __restrict__ hcbf,
                short* __restrict__ xeh, const float* __restrict__ E)
{
    int gid = blockIdx.x * 256 + threadIdx.x;
    int b = gid >> 9, d = gid & 511;
    float h0 = e_h[gid], c0 = e_c[gid];
    c[gid] = c0;
    hcbf[gid] = (short)f2b(h0 + c0);
    xeh[(size_t)b * 1024 + 512 + d] = (short)f2b(h0);
    xeh[(size_t)b * 1024 + d] = (short)f2b(E[d]);   // token 0 (SOS)
}

__global__ __launch_bounds__(256)
void transpose_cast(const float* __restrict__ in, short* __restrict__ out,
                    int N, int ostride, int koff, int gate_perm)
{
    __shared__ float tile[64][65];
    int t = threadIdx.x;
    int n0 = blockIdx.x * 64, k0 = blockIdx.y * 64;
    int cc = t & 63, r4 = t >> 6;
    for (int i = 0; i < 16; ++i) {
        int r = i * 4 + r4;
        tile[r][cc] = in[(size_t)(k0 + r) * N + n0 + cc];
    }
    __syncthreads();
    for (int i = 0; i < 16; ++i) {
        int nr = i * 4 + r4;
        int ng = n0 + nr;
        int np = gate_perm ? ((ng & 511) * 4 + (ng >> 9)) : ng;
        out[(size_t)np * ostride + koff + k0 + cc] = (short)f2b(tile[cc][nr]);
    }
}

__global__ __launch_bounds__(256)
void cast_bf16_v4(const float* __restrict__ in, short* __restrict__ out, int n4)
{
    int i = blockIdx.x * 256 + threadIdx.x;
    int stride = gridDim.x * 256;
    for (; i < n4; i += stride) {
        f32x4 v = ((const f32x4*)in)[i];
        s16x4 o;
        for (int j = 0; j < 4; ++j) o[j] = (short)f2b(v[j]);
        ((s16x4*)out)[i] = o;
    }
}

__global__ __launch_bounds__(256)
void make_bcat(const float* __restrict__ b_ih, const float* __restrict__ b_hh, float* __restrict__ bcat)
{
    int i = blockIdx.x * 256 + threadIdx.x;
    if (i < 2048) {
        int np = (i & 511) * 4 + (i >> 9);
        bcat[np] = b_ih[i] + b_hh[i];
    }
}

extern "C" void kernel_launch(void* const* d_in, const int* in_sizes, int n_in,
                              void* d_out, int out_size, void* d_ws, size_t ws_size,
                              hipStream_t stream)
{
    const float* e_all  = (const float*)d_in[0];
    const float* e_h    = (const float*)d_in[1];
    const float* e_c    = (const float*)d_in[2];
    const int*   target = (const int*)d_in[3];
    const float* E      = (const float*)d_in[4];
    const float* Wa     = (const float*)d_in[5];
    const float* ba     = (const float*)d_in[6];
    const float* Ua     = (const float*)d_in[7];
    const float* bu     = (const float*)d_in[8];
    const float* Va     = (const float*)d_in[9];
    const float* bv     = (const float*)d_in[10];
    const float* W_ih   = (const float*)d_in[11];
    const float* b_ih   = (const float*)d_in[12];
    const float* W_hh   = (const float*)d_in[13];
    const float* b_hh   = (const float*)d_in[14];
    const float* W_out  = (const float*)d_in[15];
    const float* b_out  = (const float*)d_in[16];

    char* ws = (char*)d_ws;
    size_t off = 0;
    auto alloc = [&](size_t bytes) { void* p = ws + off; off += (bytes + 255) & ~255ull; return p; };
    short* ealb  = (short*)alloc((size_t)B_ * S_ * D_ * 2);
    short* kpb   = (short*)alloc((size_t)B_ * S_ * D_ * 2);
    unsigned char* kp8 = (unsigned char*)alloc((size_t)B_ * S_ * D_);
    unsigned char* ea8 = (unsigned char*)alloc((size_t)B_ * S_ * D_);
    short* WaT   = (short*)alloc((size_t)D_ * D_ * 2);
    short* UaT   = (short*)alloc((size_t)D_ * D_ * 2);
    short* WehT  = (short*)alloc((size_t)2048 * 1024 * 2);
    short* WctxT = (short*)alloc((size_t)2048 * 512 * 2);
    short* WoutT = (short*)alloc((size_t)V_ * D_ * 2);
    float* bcat  = (float*)alloc(2048 * 4);
    short* qbf   = (short*)alloc((size_t)B_ * D_ * 2);
    short* vab   = (short*)alloc((size_t)D_ * 2);
    short* xeh   = (short*)alloc((size_t)B_ * 1024 * 2);
    short* ctxb  = (short*)alloc((size_t)B_ * D_ * 2);
    short* gp0   = (short*)alloc((size_t)B_ * 2048 * 2);
    short* gp1   = (short*)alloc((size_t)B_ * 2048 * 2);
    short* hcbf  = (short*)alloc((size_t)B_ * D_ * 2);
    short* h2bf  = (short*)alloc((size_t)B_ * D_ * 2);
    float* cst   = (float*)alloc((size_t)B_ * D_ * 4);
    unsigned* flags = (unsigned*)alloc((size_t)T_ * 8 * 4);
    if (off > ws_size) return;

    float* out_logits = (float*)d_out;                        // [B,T,V]
    float* out_attn   = (float*)d_out + (size_t)B_ * T_ * V_; // [B,T,S]

    // ---- precompute ----
    zero_flags<<<4, 256, 0, stream>>>(flags, T_ * 8);
    cast_bf16_v4<<<4096, 256, 0, stream>>>(e_all, ealb, B_ * S_ * D_ / 4);
    cast_fp8_v4<<<4096, 256, 0, stream>>>(e_all, ea8, B_ * S_ * D_ / 4);
    cast_bf16_v4<<<1,    256, 0, stream>>>(Va, vab, D_ / 4);
    transpose_cast<<<dim3(8, 8),  256, 0, stream>>>(Wa,  WaT,  512,  512, 0, 0);
    transpose_cast<<<dim3(8, 8),  256, 0, stream>>>(Ua,  UaT,  512,  512, 0, 0);
    transpose_cast<<<dim3(32, 8), 256, 0, stream>>>(W_ih,              WehT,  2048, 1024, 0,   1);
    transpose_cast<<<dim3(32, 8), 256, 0, stream>>>(W_ih + 512 * 2048, WctxT, 2048, 512,  0,   1);
    transpose_cast<<<dim3(32, 8), 256, 0, stream>>>(W_hh,              WehT,  2048, 1024, 512, 1);
    transpose_cast<<<dim3(2, 8),  256, 0, stream>>>(W_out, WoutT, 128, 512, 0, 0);
    make_bcat<<<8, 256, 0, stream>>>(b_ih, b_hh, bcat);
    gemm64<<<dim3(8, 1024), 256, 0, stream>>>(ealb, UaT, bu, kpb, B_ * S_, 512, 512);
    transpose_kp8<<<512, 256, 0, stream>>>(kpb, kp8);
    init_state<<<1024, 256, 0, stream>>>(e_h, e_c, cst, hcbf, xeh, E);

    P pp;
    pp.target = target; pp.E = E; pp.bv = bv; pp.ba = ba; pp.bout = b_out; pp.bcat = bcat;
    pp.vab = vab; pp.ea8 = ea8; pp.kp8 = kp8;
    pp.WaT = WaT; pp.WehT = WehT; pp.WctxT = WctxT; pp.WoutT = WoutT;
    pp.qbf = qbf; pp.ctxb = ctxb; pp.gp0 = gp0; pp.gp1 = gp1;
    pp.cst = cst; pp.hcbf = hcbf; pp.h2bf = h2bf; pp.xeh = xeh;
    pp.flags = flags;
    pp.out_logits = out_logits; pp.out_attn = out_attn;

    // q(0) + gp0 from initial state
    kInit<<<192, 256, 0, stream>>>(pp);

    // ---- sequential decode: 2 dispatches per step ----
    for (int t = 0; t < T_; ++t) {
        kA<<<512, 256, 0, stream>>>(pp, t);
        kBC<<<456, 256, 0, stream>>>(pp, t);
    }
    (void)n_in; (void)in_sizes; (void)out_size;
}

// Round 13
// 9072.506 us; speedup vs baseline: 3.3270x; 1.6606x over previous
//
#include <hip/hip_runtime.h>

#define B_ 512
#define S_ 128
#define T_ 128
#define D_ 512
#define V_ 128
#define LDW 72

typedef __attribute__((ext_vector_type(8))) short s16x8;
typedef __attribute__((ext_vector_type(4))) short s16x4;
typedef __attribute__((ext_vector_type(4))) float f32x4;

__device__ __forceinline__ float b2f(unsigned short h) {
    union { unsigned int u; float f; } x; x.u = ((unsigned int)h) << 16; return x.f;
}
__device__ __forceinline__ unsigned short f2b(float f) {
    union { float f; unsigned int u; } x; x.f = f;
    unsigned int u = x.u; u += 0x7FFFu + ((u >> 16) & 1u);
    return (unsigned short)(u >> 16);
}
#if __has_builtin(__builtin_amdgcn_rcpf)
__device__ __forceinline__ float rcp_f(float x) { return __builtin_amdgcn_rcpf(x); }
#else
__device__ __forceinline__ float rcp_f(float x) { return 1.0f / x; }
#endif
__device__ __forceinline__ float sigm(float x) { return rcp_f(1.0f + __expf(-x)); }
__device__ __forceinline__ float tanh_fast(float x) {
    float e = __expf(2.0f * fabsf(x));
    float r = 1.0f - 2.0f * rcp_f(e + 1.0f);
    return copysignf(r, x);
}
__device__ __forceinline__ float tanh_pade(float x) {
    float t = x * x;
    float num = x * fmaf(t, 105.0f + t, 945.0f);
    float den = fmaf(t, fmaf(t, 15.0f, 420.0f), 945.0f);
    float r = num * rcp_f(den);
    return fminf(1.0f, fmaxf(-1.0f, r));
}

#if __has_builtin(__builtin_amdgcn_cvt_f32_fp8)
__device__ __forceinline__ f32x4 fp8x4_dec(unsigned w) {
    f32x4 r;
    r[0] = __builtin_amdgcn_cvt_f32_fp8(w, 0);
    r[1] = __builtin_amdgcn_cvt_f32_fp8(w, 1);
    r[2] = __builtin_amdgcn_cvt_f32_fp8(w, 2);
    r[3] = __builtin_amdgcn_cvt_f32_fp8(w, 3);
    return r;
}
#else
__device__ __forceinline__ float fp8_dec_sw(unsigned w, int j) {
    unsigned char v = (w >> (8 * j)) & 0xFF;
    unsigned s = v >> 7, e = (v >> 3) & 0xF, m = v & 7;
    float r = (e == 0) ? ldexpf((float)m, -9) : ldexpf((float)(8 + m), (int)e - 10);
    return s ? -r : r;
}
__device__ __forceinline__ f32x4 fp8x4_dec(unsigned w) {
    f32x4 r;
    r[0] = fp8_dec_sw(w, 0); r[1] = fp8_dec_sw(w, 1);
    r[2] = fp8_dec_sw(w, 2); r[3] = fp8_dec_sw(w, 3);
    return r;
}
#endif

#if __has_builtin(__builtin_amdgcn_cvt_pk_fp8_f32)
__device__ __forceinline__ unsigned pk_fp8(float a, float b, float c, float d) {
    int r = 0;
    r = __builtin_amdgcn_cvt_pk_fp8_f32(a, b, r, false);
    r = __builtin_amdgcn_cvt_pk_fp8_f32(c, d, r, true);
    return (unsigned)r;
}
#else
__device__ __forceinline__ unsigned char f32_to_fp8_sw(float x) {
    unsigned s = x < 0.f ? 0x80u : 0u; float a = fabsf(x);
    if (a != a) return (unsigned char)(s | 0x7F);
    if (a >= 448.f) return (unsigned char)(s | 0x7E);
    if (a < 0.001953125f) { int m = (int)rintf(a * 512.0f); return (unsigned char)(s | (m > 7 ? 0x08 : m)); }
    int e; float fr = frexpf(a, &e);
    int m = (int)rintf(fr * 16.0f - 8.0f);
    int ee = e - 1 + 7;
    if (m == 8) { m = 0; ee += 1; }
    if (ee <= 0) { int mm = (int)rintf(a * 512.f); return (unsigned char)(s | (mm > 7 ? 0x08 : mm)); }
    if (ee >= 16) return (unsigned char)(s | 0x7E);
    return (unsigned char)(s | (ee << 3) | m);
}
__device__ __forceinline__ unsigned pk_fp8(float a, float b, float c, float d) {
    return (unsigned)f32_to_fp8_sw(a) | ((unsigned)f32_to_fp8_sw(b) << 8)
         | ((unsigned)f32_to_fp8_sw(c) << 16) | ((unsigned)f32_to_fp8_sw(d) << 24);
}
#endif

// ---------------- coherent (agent-scope, write-through) access helpers ----------------
__device__ __forceinline__ s16x8 coh_load16(const short* p) {
    union { unsigned long long u[2]; s16x8 v; } x;
    x.u[0] = __hip_atomic_load((unsigned long long*)p,     __ATOMIC_RELAXED, __HIP_MEMORY_SCOPE_AGENT);
    x.u[1] = __hip_atomic_load((unsigned long long*)p + 1, __ATOMIC_RELAXED, __HIP_MEMORY_SCOPE_AGENT);
    return x.v;
}
__device__ __forceinline__ void coh_store4(void* p, unsigned v) {
    __hip_atomic_store((unsigned*)p, v, __ATOMIC_RELAXED, __HIP_MEMORY_SCOPE_AGENT);
}

struct P {
    const int* target;
    const float* E; const float* bv; const float* ba; const float* bout; const float* bcat;
    const short* vab;
    const unsigned char* ea8; const unsigned char* kp8;
    const short* WaT; const short* WehT; const short* WctxT; const short* WoutT;
    short* qbf; short* ctxb; short* gp0; short* gp1;
    float* cst; short* hcbf; short* h2bf; short* xeh;
    unsigned* flags;
    float* out_logits; float* out_attn;
};

struct GateS { short As[64][LDW]; short Bs[64][LDW]; float gt[64][65]; };
struct PG2   { short As[128][LDW]; short Bs[64][LDW]; };
struct OutS  { short As[64][LDW]; short Bs[128][LDW]; };
union SharedBC { GateS g; PG2 pg; OutS o; };

// ---------------- fence-free flag sync ----------------
__device__ __forceinline__ void signal_flag(unsigned* f) {
    asm volatile("s_waitcnt vmcnt(0)" ::: "memory");  // this wave's sc1 stores done
    __syncthreads();                                  // all waves drained (compiler adds waitcnt)
    if (threadIdx.x == 0)
        __hip_atomic_fetch_add(f, 1u, __ATOMIC_RELAXED, __HIP_MEMORY_SCOPE_AGENT);
}
__device__ __forceinline__ void wait_flag(unsigned* f, unsigned tgt) {
    if (threadIdx.x == 0) {
        while (__hip_atomic_load(f, __ATOMIC_RELAXED, __HIP_MEMORY_SCOPE_AGENT) < tgt)
            __builtin_amdgcn_s_sleep(2);
    }
    __syncthreads();                                  // no fence: produced data read via coh loads
}

// ================= kA: attention, 512 blocks (1 row each) =================
__global__ __launch_bounds__(256, 2) void kA(P p, int step)
{
    __shared__ float scp[4][64];
    __shared__ float wbuf[S_];
    __shared__ float cpart[4][D_];
    const int b = blockIdx.x;
    const int t = threadIdx.x, lane = t & 63, wave = t >> 6;
    {
        const int sg = wave & 1, dh = wave >> 1;
        const int s = sg * 64 + lane;
        const unsigned char* kb = p.kp8 + (size_t)b * (S_ * D_);
        const short* qv = p.qbf + (size_t)b * D_;
        float acc = 0.f;
        #pragma unroll 4
        for (int i = 0; i < 16; ++i) {
            int g = dh * 16 + i;
            uint4 kw = *(const uint4*)(kb + ((size_t)g * 128 + s) * 16);
            const short* qg = qv + g * 16;
            const short* vg = p.vab + g * 16;
            s16x8 q0 = *(const s16x8*)(qg), q1 = *(const s16x8*)(qg + 8);
            s16x8 v0 = *(const s16x8*)(vg), v1 = *(const s16x8*)(vg + 8);
            f32x4 ka = fp8x4_dec(kw.x), kb4 = fp8x4_dec(kw.y);
            f32x4 kc = fp8x4_dec(kw.z), kd = fp8x4_dec(kw.w);
            #pragma unroll
            for (int j = 0; j < 4; ++j) {
                acc += tanh_pade(b2f((unsigned short)q0[j])     + ka[j])  * b2f((unsigned short)v0[j]);
                acc += tanh_pade(b2f((unsigned short)q0[4 + j]) + kb4[j]) * b2f((unsigned short)v0[4 + j]);
                acc += tanh_pade(b2f((unsigned short)q1[j])     + kc[j])  * b2f((unsigned short)v1[j]);
                acc += tanh_pade(b2f((unsigned short)q1[4 + j]) + kd[j])  * b2f((unsigned short)v1[4 + j]);
            }
        }
        scp[wave][lane] = acc;
    }
    __syncthreads();
    if (wave == 0) {
        const float bvv = p.bv[0];
        float v0 = scp[0][lane] + scp[2][lane] + bvv;
        float v1 = scp[1][lane] + scp[3][lane] + bvv;
        float m = fmaxf(v0, v1);
        #pragma unroll
        for (int o = 32; o >= 1; o >>= 1) m = fmaxf(m, __shfl_xor(m, o));
        float e0 = __expf(v0 - m), e1 = __expf(v1 - m);
        float su = e0 + e1;
        #pragma unroll
        for (int o = 32; o >= 1; o >>= 1) su += __shfl_xor(su, o);
        float inv = rcp_f(su);
        float w0 = e0 * inv, w1 = e1 * inv;
        wbuf[lane] = w0; wbuf[lane + 64] = w1;
        float* ao = p.out_attn + ((size_t)b * T_ + step) * S_;
        ao[lane] = w0; ao[lane + 64] = w1;
    }
    __syncthreads();
    {
        const int d0 = lane * 8;
        f32x4 aA = {0.f,0.f,0.f,0.f}, aB = {0.f,0.f,0.f,0.f};
        const unsigned char* eb = p.ea8 + (size_t)b * S_ * D_ + d0;
        #pragma unroll 4
        for (int i = 0; i < 32; ++i) {
            int s = wave * 32 + i;
            float wv = wbuf[s];
            uint2 ev = *(const uint2*)(eb + (size_t)s * D_);
            f32x4 ex = fp8x4_dec(ev.x), ey = fp8x4_dec(ev.y);
            #pragma unroll
            for (int j = 0; j < 4; ++j) aA[j] += wv * ex[j];
            #pragma unroll
            for (int j = 0; j < 4; ++j) aB[j] += wv * ey[j];
        }
        *(f32x4*)&cpart[wave][d0]     = aA;
        *(f32x4*)&cpart[wave][d0 + 4] = aB;
    }
    __syncthreads();
    {
        int dd = t * 2;
        float v0 = cpart[0][dd]   + cpart[1][dd]   + cpart[2][dd]   + cpart[3][dd];
        float v1 = cpart[0][dd+1] + cpart[1][dd+1] + cpart[2][dd+1] + cpart[3][dd+1];
        short2 o2; o2.x = (short)f2b(v0); o2.y = (short)f2b(v1);
        *(short2*)(p.ctxb + (size_t)b * D_ + dd) = o2;
    }
}

// ---------------- fgate (64x64 tile, K=512 ctx) + gp(read) + fused LSTM (coherent stores) ---------
__device__ __forceinline__ void fgate_phase(const P& p, GateS& sh, int bid, int step,
                                            const short* __restrict__ gprd)
{
    const int t = threadIdx.x, lane = t & 63, wave = t >> 6;
    const int wr = wave >> 1, wc = wave & 1;
    const int lrow = lane & 15, kq = lane >> 4;
    const int srow = t >> 3, sseg = t & 7;
    const int m0 = (bid >> 5) * 64, n0 = (bid & 31) * 64;
    f32x4 acc[2][2] = {};
    for (int k0 = 0; k0 < 512; k0 += 64) {
        s16x8 va0 = *(const s16x8*)(p.ctxb + (size_t)(m0 + srow) * 512 + k0 + sseg * 8);
        s16x8 va1 = *(const s16x8*)(p.ctxb + (size_t)(m0 + srow + 32) * 512 + k0 + sseg * 8);
        s16x8 vb0 = *(const s16x8*)(p.WctxT + (size_t)(n0 + srow) * 512 + k0 + sseg * 8);
        s16x8 vb1 = *(const s16x8*)(p.WctxT + (size_t)(n0 + srow + 32) * 512 + k0 + sseg * 8);
        __syncthreads();
        *(s16x8*)(&sh.As[srow][sseg * 8]) = va0;
        *(s16x8*)(&sh.As[srow + 32][sseg * 8]) = va1;
        *(s16x8*)(&sh.Bs[srow][sseg * 8]) = vb0;
        *(s16x8*)(&sh.Bs[srow + 32][sseg * 8]) = vb1;
        __syncthreads();
        #pragma unroll
        for (int kk = 0; kk < 64; kk += 32) {
            s16x8 af0 = *(const s16x8*)(&sh.As[wr * 32 + lrow][kk + kq * 8]);
            s16x8 af1 = *(const s16x8*)(&sh.As[wr * 32 + 16 + lrow][kk + kq * 8]);
            s16x8 bf0 = *(const s16x8*)(&sh.Bs[wc * 32 + lrow][kk + kq * 8]);
            s16x8 bf1 = *(const s16x8*)(&sh.Bs[wc * 32 + 16 + lrow][kk + kq * 8]);
            acc[0][0] = __builtin_amdgcn_mfma_f32_16x16x32_bf16(af0, bf0, acc[0][0], 0, 0, 0);
            acc[0][1] = __builtin_amdgcn_mfma_f32_16x16x32_bf16(af0, bf1, acc[0][1], 0, 0, 0);
            acc[1][0] = __builtin_amdgcn_mfma_f32_16x16x32_bf16(af1, bf0, acc[1][0], 0, 0, 0);
            acc[1][1] = __builtin_amdgcn_mfma_f32_16x16x32_bf16(af1, bf1, acc[1][1], 0, 0, 0);
        }
    }
    #pragma unroll
    for (int m2 = 0; m2 < 2; ++m2)
        #pragma unroll
        for (int n2 = 0; n2 < 2; ++n2) {
            int cl = wc * 32 + n2 * 16 + lrow;
            #pragma unroll
            for (int j = 0; j < 4; ++j) {
                int rl = wr * 32 + m2 * 16 + kq * 4 + j;
                sh.gt[rl][cl] = acc[m2][n2][j]
                              + b2f((unsigned short)gprd[(size_t)(m0 + rl) * 2048 + n0 + cl]);
            }
        }
    __syncthreads();
    // LSTM epilogue: 2 passes, each thread handles (row, dim-pair) -> packed 4B coherent stores
    const int dp = t & 7, rr = t >> 3;
    #pragma unroll
    for (int pass = 0; pass < 2; ++pass) {
        int row = pass * 32 + rr;
        int b = m0 + row;
        int dl0 = dp * 2;
        float gi0 = sh.gt[row][dl0 * 4 + 0], gf0 = sh.gt[row][dl0 * 4 + 1];
        float gg0 = sh.gt[row][dl0 * 4 + 2], go0 = sh.gt[row][dl0 * 4 + 3];
        float gi1 = sh.gt[row][dl0 * 4 + 4], gf1 = sh.gt[row][dl0 * 4 + 5];
        float gg1 = sh.gt[row][dl0 * 4 + 6], go1 = sh.gt[row][dl0 * 4 + 7];
        int d = (n0 >> 2) + dl0;
        float2 cv = *(const float2*)(p.cst + (size_t)b * 512 + d);
        float c20 = sigm(gf0) * cv.x + sigm(gi0) * tanh_fast(gg0);
        float h20 = sigm(go0) * tanh_fast(c20);
        float c21 = sigm(gf1) * cv.y + sigm(gi1) * tanh_fast(gg1);
        float h21 = sigm(go1) * tanh_fast(c21);
        float2 cw; cw.x = c20; cw.y = c21;
        *(float2*)(p.cst + (size_t)b * 512 + d) = cw;
        unsigned hcp = (unsigned)f2b(h20 + c20) | ((unsigned)f2b(h21 + c21) << 16);
        unsigned h2p = (unsigned)f2b(h20) | ((unsigned)f2b(h21) << 16);
        coh_store4(p.hcbf + (size_t)b * 512 + d, hcp);
        coh_store4(p.h2bf + (size_t)b * 512 + d, h2p);
        coh_store4(p.xeh + (size_t)b * 1024 + 512 + d, h2p);
        int tok = p.target[b * T_ + step];
        unsigned ep = (unsigned)f2b(p.E[(size_t)tok * 512 + d])
                    | ((unsigned)f2b(p.E[(size_t)tok * 512 + d + 1]) << 16);
        coh_store4(p.xeh + (size_t)b * 1024 + d, ep);
    }
}

// ---------------- q GEMM 64x64 (M=N=K=512) -> bf16 q (coherent A loads) ----------------
__device__ __forceinline__ void q64_phase(const P& p, OutS& sh, int bid)
{
    const int t = threadIdx.x, lane = t & 63, wave = t >> 6;
    const int wr = wave >> 1, wc = wave & 1;
    const int lrow = lane & 15, kq = lane >> 4;
    const int srow = t >> 3, sseg = t & 7;
    const int m0 = (bid >> 3) * 64, n0 = (bid & 7) * 64;
    f32x4 acc[2][2] = {};
    for (int k0 = 0; k0 < 512; k0 += 64) {
        s16x8 va0 = coh_load16(p.hcbf + (size_t)(m0 + srow) * 512 + k0 + sseg * 8);
        s16x8 va1 = coh_load16(p.hcbf + (size_t)(m0 + srow + 32) * 512 + k0 + sseg * 8);
        s16x8 vb0 = *(const s16x8*)(p.WaT + (size_t)(n0 + srow) * 512 + k0 + sseg * 8);
        s16x8 vb1 = *(const s16x8*)(p.WaT + (size_t)(n0 + srow + 32) * 512 + k0 + sseg * 8);
        __syncthreads();
        *(s16x8*)(&sh.As[srow][sseg * 8]) = va0;
        *(s16x8*)(&sh.As[srow + 32][sseg * 8]) = va1;
        *(s16x8*)(&sh.Bs[srow][sseg * 8]) = vb0;
        *(s16x8*)(&sh.Bs[srow + 32][sseg * 8]) = vb1;
        __syncthreads();
        #pragma unroll
        for (int kk = 0; kk < 64; kk += 32) {
            s16x8 af0 = *(const s16x8*)(&sh.As[wr * 32 + lrow][kk + kq * 8]);
            s16x8 af1 = *(const s16x8*)(&sh.As[wr * 32 + 16 + lrow][kk + kq * 8]);
            s16x8 bf0 = *(const s16x8*)(&sh.Bs[wc * 32 + lrow][kk + kq * 8]);
            s16x8 bf1 = *(const s16x8*)(&sh.Bs[wc * 32 + 16 + lrow][kk + kq * 8]);
            acc[0][0] = __builtin_amdgcn_mfma_f32_16x16x32_bf16(af0, bf0, acc[0][0], 0, 0, 0);
            acc[0][1] = __builtin_amdgcn_mfma_f32_16x16x32_bf16(af0, bf1, acc[0][1], 0, 0, 0);
            acc[1][0] = __builtin_amdgcn_mfma_f32_16x16x32_bf16(af1, bf0, acc[1][0], 0, 0, 0);
            acc[1][1] = __builtin_amdgcn_mfma_f32_16x16x32_bf16(af1, bf1, acc[1][1], 0, 0, 0);
        }
    }
    #pragma unroll
    for (int m2 = 0; m2 < 2; ++m2)
        #pragma unroll
        for (int n2 = 0; n2 < 2; ++n2) {
            int col = n0 + wc * 32 + n2 * 16 + lrow;
            float bvv = p.ba[col];
            #pragma unroll
            for (int j = 0; j < 4; ++j) {
                int row = m0 + wr * 32 + m2 * 16 + kq * 4 + j;
                p.qbf[(size_t)row * 512 + col] = (short)f2b(acc[m2][n2][j] + bvv);
            }
        }
}

// ---------------- pgate full-K (128x64 tile, K=1024) (coherent A loads) ----------------
__device__ __forceinline__ void pgate_full(const P& p, PG2& sh, int bid2, short* __restrict__ gpw)
{
    const int t = threadIdx.x, lane = t & 63, wave = t >> 6;
    const int lrow = lane & 15, kq = lane >> 4;
    const int m0 = (bid2 >> 5) * 128, n0 = (bid2 & 31) * 64;
    f32x4 acc[2][4] = {};
    for (int k0 = 0; k0 < 1024; k0 += 64) {
        s16x8 va[4], vb[2];
        #pragma unroll
        for (int r = 0; r < 4; ++r) {
            int idx = r * 256 + t, row = idx >> 3, seg = idx & 7;
            va[r] = coh_load16(p.xeh + (size_t)(m0 + row) * 1024 + k0 + seg * 8);
        }
        #pragma unroll
        for (int r = 0; r < 2; ++r) {
            int idx = r * 256 + t, row = idx >> 3, seg = idx & 7;
            vb[r] = *(const s16x8*)(p.WehT + (size_t)(n0 + row) * 1024 + k0 + seg * 8);
        }
        __syncthreads();
        #pragma unroll
        for (int r = 0; r < 4; ++r) {
            int idx = r * 256 + t, row = idx >> 3, seg = idx & 7;
            *(s16x8*)(&sh.As[row][seg * 8]) = va[r];
        }
        #pragma unroll
        for (int r = 0; r < 2; ++r) {
            int idx = r * 256 + t, row = idx >> 3, seg = idx & 7;
            *(s16x8*)(&sh.Bs[row][seg * 8]) = vb[r];
        }
        __syncthreads();
        #pragma unroll
        for (int kk = 0; kk < 64; kk += 32) {
            s16x8 af[2], bf[4];
            af[0] = *(const s16x8*)(&sh.As[wave * 32 + lrow][kk + kq * 8]);
            af[1] = *(const s16x8*)(&sh.As[wave * 32 + 16 + lrow][kk + kq * 8]);
            #pragma unroll
            for (int f = 0; f < 4; ++f)
                bf[f] = *(const s16x8*)(&sh.Bs[f * 16 + lrow][kk + kq * 8]);
            #pragma unroll
            for (int m2 = 0; m2 < 2; ++m2)
                #pragma unroll
                for (int n2 = 0; n2 < 4; ++n2)
                    acc[m2][n2] = __builtin_amdgcn_mfma_f32_16x16x32_bf16(af[m2], bf[n2], acc[m2][n2], 0, 0, 0);
        }
    }
    #pragma unroll
    for (int m2 = 0; m2 < 2; ++m2)
        #pragma unroll
        for (int n2 = 0; n2 < 4; ++n2) {
            int col = n0 + n2 * 16 + lrow;
            float bvv = p.bcat[col];
            #pragma unroll
            for (int j = 0; j < 4; ++j) {
                int row = m0 + wave * 32 + m2 * 16 + kq * 4 + j;
                gpw[(size_t)row * 2048 + col] = (short)f2b(acc[m2][n2][j] + bvv);
            }
        }
}

// ---------------- out GEMM (64 rows, N=128, K=512) + fused log_softmax (coherent A loads) ---------
__device__ __forceinline__ void out_phase(const P& p, OutS& sh, int obid, int step)
{
    const int t = threadIdx.x, lane = t & 63, wave = t >> 6;
    const int lrow = lane & 15, kq = lane >> 4;
    const int srow = t >> 3, sseg = t & 7;
    const int m0 = obid * 64;
    f32x4 acc[8] = {};
    for (int k0 = 0; k0 < 512; k0 += 64) {
        s16x8 va0 = coh_load16(p.h2bf + (size_t)(m0 + srow) * 512 + k0 + sseg * 8);
        s16x8 va1 = coh_load16(p.h2bf + (size_t)(m0 + srow + 32) * 512 + k0 + sseg * 8);
        s16x8 vb[4];
        #pragma unroll
        for (int p4 = 0; p4 < 4; ++p4)
            vb[p4] = *(const s16x8*)(p.WoutT + (size_t)(srow + p4 * 32) * 512 + k0 + sseg * 8);
        __syncthreads();
        *(s16x8*)(&sh.As[srow][sseg * 8]) = va0;
        *(s16x8*)(&sh.As[srow + 32][sseg * 8]) = va1;
        #pragma unroll
        for (int p4 = 0; p4 < 4; ++p4) *(s16x8*)(&sh.Bs[srow + p4 * 32][sseg * 8]) = vb[p4];
        __syncthreads();
        #pragma unroll
        for (int kk = 0; kk < 64; kk += 32) {
            s16x8 a = *(const s16x8*)(&sh.As[wave * 16 + lrow][kk + kq * 8]);
            #pragma unroll
            for (int f = 0; f < 8; ++f) {
                s16x8 b = *(const s16x8*)(&sh.Bs[f * 16 + lrow][kk + kq * 8]);
                acc[f] = __builtin_amdgcn_mfma_f32_16x16x32_bf16(a, b, acc[f], 0, 0, 0);
            }
        }
    }
    float colb[8];
    #pragma unroll
    for (int f = 0; f < 8; ++f) colb[f] = p.bout[f * 16 + lrow];
    #pragma unroll
    for (int j = 0; j < 4; ++j) {
        float v[8]; float mx = -1e30f;
        #pragma unroll
        for (int f = 0; f < 8; ++f) { v[f] = acc[f][j] + colb[f]; mx = fmaxf(mx, v[f]); }
        #pragma unroll
        for (int o = 1; o < 16; o <<= 1) mx = fmaxf(mx, __shfl_xor(mx, o));
        float sum = 0.f;
        #pragma unroll
        for (int f = 0; f < 8; ++f) sum += __expf(v[f] - mx);
        #pragma unroll
        for (int o = 1; o < 16; o <<= 1) sum += __shfl_xor(sum, o);
        float lse = mx + __logf(sum);
        int row = m0 + wave * 16 + kq * 4 + j;
        float* orow = p.out_logits + ((size_t)row * T_ + step) * V_;
        #pragma unroll
        for (int f = 0; f < 8; ++f) orow[f * 16 + lrow] = v[f] - lse;
    }
}

// ===== kBC: fgate(0..255, producers) | q(256..319) | pgate(320..447) | out(448..455) =====
__global__ __launch_bounds__(256, 2) void kBC(P p, int step)
{
    __shared__ SharedBC sh;
    const int bid = blockIdx.x;
    unsigned* fl = p.flags + step * 8;
    short* gprd = (step & 1) ? p.gp1 : p.gp0;
    short* gpwr = (step & 1) ? p.gp0 : p.gp1;
    if (bid < 256) {
        fgate_phase(p, sh.g, bid, step, gprd);
        signal_flag(&fl[bid >> 5]);
    } else if (bid < 320) {
        int qb = bid - 256;
        wait_flag(&fl[qb >> 3], 32);
        q64_phase(p, sh.o, qb);
    } else if (bid < 448) {
        int pb = bid - 320;
        int mg = (pb >> 5) * 2;
        wait_flag(&fl[mg], 32);
        wait_flag(&fl[mg + 1], 32);
        pgate_full(p, sh.pg, pb, gpwr);
    } else {
        int ob = bid - 448;
        wait_flag(&fl[ob], 32);
        out_phase(p, sh.o, ob, step);
    }
}

// kInit: q(0..63) + pgate(64..191) from initial state; writes gp0
__global__ __launch_bounds__(256, 2) void kInit(P p)
{
    __shared__ SharedBC sh;
    const int bid = blockIdx.x;
    if (bid < 64) q64_phase(p, sh.o, bid);
    else          pgate_full(p, sh.pg, bid - 64, p.gp0);
}

__global__ __launch_bounds__(256) void zero_flags(unsigned* f, int n)
{
    int i = blockIdx.x * 256 + threadIdx.x;
    if (i < n) f[i] = 0;
}

// ---------------- precompute kernels ----------------
__global__ __launch_bounds__(256)
void gemm64(const short* __restrict__ A, const short* __restrict__ Bt,
            const float* __restrict__ bias, short* __restrict__ Cp,
            int M, int N, int K)
{
    __shared__ __align__(16) short As[64][LDW];
    __shared__ __align__(16) short Bs[64][LDW];
    const int t = threadIdx.x;
    const int lane = t & 63, wave = t >> 6;
    const int wr = wave >> 1, wc = wave & 1;
    const int lrow = lane & 15, kq = lane >> 4;
    const int m0 = blockIdx.y * 64, n0 = blockIdx.x * 64;
    const int srow = t >> 3, sseg = t & 7;
    f32x4 acc[2][2] = {};
    for (int k0 = 0; k0 < K; k0 += 64) {
        s16x8 va0 = *(const s16x8*)(A + (size_t)(m0 + srow) * K + k0 + sseg * 8);
        s16x8 va1 = *(const s16x8*)(A + (size_t)(m0 + srow + 32) * K + k0 + sseg * 8);
        s16x8 vb0 = *(const s16x8*)(Bt + (size_t)(n0 + srow) * K + k0 + sseg * 8);
        s16x8 vb1 = *(const s16x8*)(Bt + (size_t)(n0 + srow + 32) * K + k0 + sseg * 8);
        __syncthreads();
        *(s16x8*)(&As[srow][sseg * 8]) = va0;
        *(s16x8*)(&As[srow + 32][sseg * 8]) = va1;
        *(s16x8*)(&Bs[srow][sseg * 8]) = vb0;
        *(s16x8*)(&Bs[srow + 32][sseg * 8]) = vb1;
        __syncthreads();
        for (int kk = 0; kk < 64; kk += 32) {
            s16x8 af[2], bf[2];
            af[0] = *(const s16x8*)(&As[wr * 32 + lrow][kk + kq * 8]);
            af[1] = *(const s16x8*)(&As[wr * 32 + 16 + lrow][kk + kq * 8]);
            bf[0] = *(const s16x8*)(&Bs[wc * 32 + lrow][kk + kq * 8]);
            bf[1] = *(const s16x8*)(&Bs[wc * 32 + 16 + lrow][kk + kq * 8]);
            for (int m2 = 0; m2 < 2; ++m2)
                for (int n2 = 0; n2 < 2; ++n2)
                    acc[m2][n2] = __builtin_amdgcn_mfma_f32_16x16x32_bf16(af[m2], bf[n2], acc[m2][n2], 0, 0, 0);
        }
    }
    for (int m2 = 0; m2 < 2; ++m2)
        for (int n2 = 0; n2 < 2; ++n2) {
            int col = n0 + wc * 32 + n2 * 16 + lrow;
            float bvv = bias ? bias[col] : 0.0f;
            for (int j = 0; j < 4; ++j) {
                int row = m0 + wr * 32 + m2 * 16 + kq * 4 + j;
                Cp[(size_t)row * N + col] = (short)f2b(acc[m2][n2][j] + bvv);
            }
        }
}

__global__ __launch_bounds__(256)
void transpose_kp8(const short* __restrict__ in, unsigned char* __restrict__ out)
{
    const int b = blockIdx.x, t = threadIdx.x;
    const size_t ibase = (size_t)b * (S_ * D_);
    for (int k = t; k < 32 * S_; k += 256) {
        int g = k >> 7, s = k & 127;
        const short* src = in + ibase + (size_t)s * D_ + g * 16;
        unsigned w[4];
        #pragma unroll
        for (int q4 = 0; q4 < 4; ++q4) {
            w[q4] = pk_fp8(b2f((unsigned short)src[q4 * 4 + 0]), b2f((unsigned short)src[q4 * 4 + 1]),
                           b2f((unsigned short)src[q4 * 4 + 2]), b2f((unsigned short)src[q4 * 4 + 3]));
        }
        uint4 o; o.x = w[0]; o.y = w[1]; o.z = w[2]; o.w = w[3];
        *(uint4*)(out + ibase + ((size_t)g * S_ + s) * 16) = o;
    }
}

__global__ __launch_bounds__(256)
void cast_fp8_v4(const float* __restrict__ in, unsigned char* __restrict__ out, int n4)
{
    int i = blockIdx.x * 256 + threadIdx.x;
    int stride = gridDim.x * 256;
    for (; i < n4; i += stride) {
        f32x4 v = ((const f32x4*)in)[i];
        ((unsigned*)out)[i] = pk_fp8(v[0], v[1], v[2], v[3]);
    }
}

__global__ __launch_bounds__(256)
void init_state(const float* __restrict__ e_h, const float* __restrict__ e_c,
                float* __restrict__ c, short* __restrict__ hcbf,
                short* __restrict__ xeh, const float* __restrict__ E)
{
    int gid = blockIdx.x * 256 + threadIdx.x;
    int b = gid >> 9, d = gid & 511;
    float h0 = e_h[gid], c0 = e_c[gid];
    c[gid] = c0;
    hcbf[gid] = (short)f2b(h0 + c0);
    xeh[(size_t)b * 1024 + 512 + d] = (short)f2b(h0);
    xeh[(size_t)b * 1024 + d] = (short)f2b(E[d]);   // token 0 (SOS)
}

__global__ __launch_bounds__(256)
void transpose_cast(const float* __restrict__ in, short* __restrict__ out,
                    int N, int ostride, int koff, int gate_perm)
{
    __shared__ float tile[64][65];
    int t = threadIdx.x;
    int n0 = blockIdx.x * 64, k0 = blockIdx.y * 64;
    int cc = t & 63, r4 = t >> 6;
    for (int i = 0; i < 16; ++i) {
        int r = i * 4 + r4;
        tile[r][cc] = in[(size_t)(k0 + r) * N + n0 + cc];
    }
    __syncthreads();
    for (int i = 0; i < 16; ++i) {
        int nr = i * 4 + r4;
        int ng = n0 + nr;
        int np = gate_perm ? ((ng & 511) * 4 + (ng >> 9)) : ng;
        out[(size_t)np * ostride + koff + k0 + cc] = (short)f2b(tile[cc][nr]);
    }
}

__global__ __launch_bounds__(256)
void cast_bf16_v4(const float* __restrict__ in, short* __restrict__ out, int n4)
{
    int i = blockIdx.x * 256 + threadIdx.x;
    int stride = gridDim.x * 256;
    for (; i < n4; i += stride) {
        f32x4 v = ((const f32x4*)in)[i];
        s16x4 o;
        for (int j = 0; j < 4; ++j) o[j] = (short)f2b(v[j]);
        ((s16x4*)out)[i] = o;
    }
}

__global__ __launch_bounds__(256)
void make_bcat(const float* __restrict__ b_ih, const float* __restrict__ b_hh, float* __restrict__ bcat)
{
    int i = blockIdx.x * 256 + threadIdx.x;
    if (i < 2048) {
        int np = (i & 511) * 4 + (i >> 9);
        bcat[np] = b_ih[i] + b_hh[i];
    }
}

extern "C" void kernel_launch(void* const* d_in, const int* in_sizes, int n_in,
                              void* d_out, int out_size, void* d_ws, size_t ws_size,
                              hipStream_t stream)
{
    const float* e_all  = (const float*)d_in[0];
    const float* e_h    = (const float*)d_in[1];
    const float* e_c    = (const float*)d_in[2];
    const int*   target = (const int*)d_in[3];
    const float* E      = (const float*)d_in[4];
    const float* Wa     = (const float*)d_in[5];
    const float* ba     = (const float*)d_in[6];
    const float* Ua     = (const float*)d_in[7];
    const float* bu     = (const float*)d_in[8];
    const float* Va     = (const float*)d_in[9];
    const float* bv     = (const float*)d_in[10];
    const float* W_ih   = (const float*)d_in[11];
    const float* b_ih   = (const float*)d_in[12];
    const float* W_hh   = (const float*)d_in[13];
    const float* b_hh   = (const float*)d_in[14];
    const float* W_out  = (const float*)d_in[15];
    const float* b_out  = (const float*)d_in[16];

    char* ws = (char*)d_ws;
    size_t off = 0;
    auto alloc = [&](size_t bytes) { void* p = ws + off; off += (bytes + 255) & ~255ull; return p; };
    short* ealb  = (short*)alloc((size_t)B_ * S_ * D_ * 2);
    short* kpb   = (short*)alloc((size_t)B_ * S_ * D_ * 2);
    unsigned char* kp8 = (unsigned char*)alloc((size_t)B_ * S_ * D_);
    unsigned char* ea8 = (unsigned char*)alloc((size_t)B_ * S_ * D_);
    short* WaT   = (short*)alloc((size_t)D_ * D_ * 2);
    short* UaT   = (short*)alloc((size_t)D_ * D_ * 2);
    short* WehT  = (short*)alloc((size_t)2048 * 1024 * 2);
    short* WctxT = (short*)alloc((size_t)2048 * 512 * 2);
    short* WoutT = (short*)alloc((size_t)V_ * D_ * 2);
    float* bcat  = (float*)alloc(2048 * 4);
    short* qbf   = (short*)alloc((size_t)B_ * D_ * 2);
    short* vab   = (short*)alloc((size_t)D_ * 2);
    short* xeh   = (short*)alloc((size_t)B_ * 1024 * 2);
    short* ctxb  = (short*)alloc((size_t)B_ * D_ * 2);
    short* gp0   = (short*)alloc((size_t)B_ * 2048 * 2);
    short* gp1   = (short*)alloc((size_t)B_ * 2048 * 2);
    short* hcbf  = (short*)alloc((size_t)B_ * D_ * 2);
    short* h2bf  = (short*)alloc((size_t)B_ * D_ * 2);
    float* cst   = (float*)alloc((size_t)B_ * D_ * 4);
    unsigned* flags = (unsigned*)alloc((size_t)T_ * 8 * 4);
    if (off > ws_size) return;

    float* out_logits = (float*)d_out;                        // [B,T,V]
    float* out_attn   = (float*)d_out + (size_t)B_ * T_ * V_; // [B,T,S]

    // ---- precompute ----
    zero_flags<<<4, 256, 0, stream>>>(flags, T_ * 8);
    cast_bf16_v4<<<4096, 256, 0, stream>>>(e_all, ealb, B_ * S_ * D_ / 4);
    cast_fp8_v4<<<4096, 256, 0, stream>>>(e_all, ea8, B_ * S_ * D_ / 4);
    cast_bf16_v4<<<1,    256, 0, stream>>>(Va, vab, D_ / 4);
    transpose_cast<<<dim3(8, 8),  256, 0, stream>>>(Wa,  WaT,  512,  512, 0, 0);
    transpose_cast<<<dim3(8, 8),  256, 0, stream>>>(Ua,  UaT,  512,  512, 0, 0);
    transpose_cast<<<dim3(32, 8), 256, 0, stream>>>(W_ih,              WehT,  2048, 1024, 0,   1);
    transpose_cast<<<dim3(32, 8), 256, 0, stream>>>(W_ih + 512 * 2048, WctxT, 2048, 512,  0,   1);
    transpose_cast<<<dim3(32, 8), 256, 0, stream>>>(W_hh,              WehT,  2048, 1024, 512, 1);
    transpose_cast<<<dim3(2, 8),  256, 0, stream>>>(W_out, WoutT, 128, 512, 0, 0);
    make_bcat<<<8, 256, 0, stream>>>(b_ih, b_hh, bcat);
    gemm64<<<dim3(8, 1024), 256, 0, stream>>>(ealb, UaT, bu, kpb, B_ * S_, 512, 512);
    transpose_kp8<<<512, 256, 0, stream>>>(kpb, kp8);
    init_state<<<1024, 256, 0, stream>>>(e_h, e_c, cst, hcbf, xeh, E);

    P pp;
    pp.target = target; pp.E = E; pp.bv = bv; pp.ba = ba; pp.bout = b_out; pp.bcat = bcat;
    pp.vab = vab; pp.ea8 = ea8; pp.kp8 = kp8;
    pp.WaT = WaT; pp.WehT = WehT; pp.WctxT = WctxT; pp.WoutT = WoutT;
    pp.qbf = qbf; pp.ctxb = ctxb; pp.gp0 = gp0; pp.gp1 = gp1;
    pp.cst = cst; pp.hcbf = hcbf; pp.h2bf = h2bf; pp.xeh = xeh;
    pp.flags = flags;
    pp.out_logits = out_logits; pp.out_attn = out_attn;

    // q(0) + gp0 from initial state
    kInit<<<192, 256, 0, stream>>>(pp);

    // ---- sequential decode: 2 dispatches per step ----
    for (int t = 0; t < T_; ++t) {
        kA<<<512, 256, 0, stream>>>(pp, t);
        kBC<<<456, 256, 0, stream>>>(pp, t);
    }
    (void)n_in; (void)in_sizes; (void)out_size;
}

// Round 15
// 7823.677 us; speedup vs baseline: 3.8581x; 1.1596x over previous
//
#include <hip/hip_runtime.h>

#define B_ 512
#define S_ 128
#define T_ 128
#define D_ 512
#define V_ 128
#define LDW 72

typedef __attribute__((ext_vector_type(8))) short s16x8;
typedef __attribute__((ext_vector_type(4))) short s16x4;
typedef __attribute__((ext_vector_type(4))) float f32x4;

__device__ __forceinline__ float b2f(unsigned short h) {
    union { unsigned int u; float f; } x; x.u = ((unsigned int)h) << 16; return x.f;
}
__device__ __forceinline__ unsigned short f2b(float f) {
    union { float f; unsigned int u; } x; x.f = f;
    unsigned int u = x.u; u += 0x7FFFu + ((u >> 16) & 1u);
    return (unsigned short)(u >> 16);
}
#if __has_builtin(__builtin_amdgcn_rcpf)
__device__ __forceinline__ float rcp_f(float x) { return __builtin_amdgcn_rcpf(x); }
#else
__device__ __forceinline__ float rcp_f(float x) { return 1.0f / x; }
#endif
__device__ __forceinline__ float sigm(float x) { return rcp_f(1.0f + __expf(-x)); }
__device__ __forceinline__ float tanh_fast(float x) {
    float e = __expf(2.0f * fabsf(x));
    float r = 1.0f - 2.0f * rcp_f(e + 1.0f);
    return copysignf(r, x);
}
__device__ __forceinline__ float tanh_pade(float x) {
    float t = x * x;
    float num = x * fmaf(t, 105.0f + t, 945.0f);
    float den = fmaf(t, fmaf(t, 15.0f, 420.0f), 945.0f);
    float r = num * rcp_f(den);
    return fminf(1.0f, fmaxf(-1.0f, r));
}

#if __has_builtin(__builtin_amdgcn_cvt_f32_fp8)
__device__ __forceinline__ f32x4 fp8x4_dec(unsigned w) {
    f32x4 r;
    r[0] = __builtin_amdgcn_cvt_f32_fp8(w, 0);
    r[1] = __builtin_amdgcn_cvt_f32_fp8(w, 1);
    r[2] = __builtin_amdgcn_cvt_f32_fp8(w, 2);
    r[3] = __builtin_amdgcn_cvt_f32_fp8(w, 3);
    return r;
}
#else
__device__ __forceinline__ float fp8_dec_sw(unsigned w, int j) {
    unsigned char v = (w >> (8 * j)) & 0xFF;
    unsigned s = v >> 7, e = (v >> 3) & 0xF, m = v & 7;
    float r = (e == 0) ? ldexpf((float)m, -9) : ldexpf((float)(8 + m), (int)e - 10);
    return s ? -r : r;
}
__device__ __forceinline__ f32x4 fp8x4_dec(unsigned w) {
    f32x4 r;
    r[0] = fp8_dec_sw(w, 0); r[1] = fp8_dec_sw(w, 1);
    r[2] = fp8_dec_sw(w, 2); r[3] = fp8_dec_sw(w, 3);
    return r;
}
#endif

#if __has_builtin(__builtin_amdgcn_cvt_pk_fp8_f32)
__device__ __forceinline__ unsigned pk_fp8(float a, float b, float c, float d) {
    int r = 0;
    r = __builtin_amdgcn_cvt_pk_fp8_f32(a, b, r, false);
    r = __builtin_amdgcn_cvt_pk_fp8_f32(c, d, r, true);
    return (unsigned)r;
}
#else
__device__ __forceinline__ unsigned char f32_to_fp8_sw(float x) {
    unsigned s = x < 0.f ? 0x80u : 0u; float a = fabsf(x);
    if (a != a) return (unsigned char)(s | 0x7F);
    if (a >= 448.f) return (unsigned char)(s | 0x7E);
    if (a < 0.001953125f) { int m = (int)rintf(a * 512.0f); return (unsigned char)(s | (m > 7 ? 0x08 : m)); }
    int e; float fr = frexpf(a, &e);
    int m = (int)rintf(fr * 16.0f - 8.0f);
    int ee = e - 1 + 7;
    if (m == 8) { m = 0; ee += 1; }
    if (ee <= 0) { int mm = (int)rintf(a * 512.f); return (unsigned char)(s | (mm > 7 ? 0x08 : mm)); }
    if (ee >= 16) return (unsigned char)(s | 0x7E);
    return (unsigned char)(s | (ee << 3) | m);
}
__device__ __forceinline__ unsigned pk_fp8(float a, float b, float c, float d) {
    return (unsigned)f32_to_fp8_sw(a) | ((unsigned)f32_to_fp8_sw(b) << 8)
         | ((unsigned)f32_to_fp8_sw(c) << 16) | ((unsigned)f32_to_fp8_sw(d) << 24);
}
#endif

struct P {
    const int* target;
    const float* E; const float* bv; const float* ba; const float* bout; const float* bcat;
    const short* vab;
    const unsigned char* ea8; const unsigned char* kp8;
    const short* Wab; const short* WehT; const short* WctxT; const short* WoutT;
    short* ctxb; short* gp;
    float* cst; short* hcbf; short* h2bf; short* xeh;
    float* out_logits; float* out_attn;
};

// attn block state (2 rows per block)
struct Attn2S {
    float hcl[2][512];    // 4KB  hc rows f32
    float part[4][512];   // 8KB  q partials, then ctx partials
    short qbls[2][512];   // 2KB  q rows bf16
    float scp[4][64];     // 1KB
    float wbuf[2][128];   // 1KB
};
struct PG2   { short As[128][LDW]; short Bs[64][LDW]; };
struct OutS  { short As[64][LDW]; short Bs[128][LDW]; };
struct GateS { short As[64][LDW]; short Bs[64][LDW]; float gt[64][65]; };
union SharedD1 { Attn2S a; PG2 pg; OutS o; };

// ---------------- attn+q: 2 rows per block; q = hc @ Wa + ba computed in-block ----------------
__device__ __forceinline__ void attn2_phase(const P& p, Attn2S& sh, int pairIdx, int step)
{
    const int t = threadIdx.x, lane = t & 63, wave = t >> 6;
    const int r = wave >> 1;          // row (0/1) this wave serves
    const int b0 = pairIdx * 2;
    // stage hc rows as f32
    for (int i = t; i < 1024; i += 256) {
        int rr = i >> 9, d = i & 511;
        sh.hcl[rr][d] = b2f((unsigned short)p.hcbf[(size_t)(b0 + rr) * 512 + d]);
    }
    __syncthreads();
    // q matvec: wave (r, kh) covers k-half, all 512 cols (8 per lane), coalesced Wab rows
    {
        const int kh = wave & 1;
        const short* wb = p.Wab + (size_t)(kh * 256) * 512 + lane * 8;
        float qa[8] = {};
        #pragma unroll 4
        for (int k = 0; k < 256; ++k) {
            s16x8 wv = *(const s16x8*)(wb + (size_t)k * 512);
            float h = sh.hcl[r][kh * 256 + k];
            #pragma unroll
            for (int j = 0; j < 8; ++j) qa[j] += h * b2f((unsigned short)wv[j]);
        }
        #pragma unroll
        for (int j = 0; j < 8; ++j) sh.part[wave][lane * 8 + j] = qa[j];
    }
    __syncthreads();
    // reduce q + ba -> bf16
    for (int i = t; i < 1024; i += 256) {
        int rr = i >> 9, c = i & 511;
        float qv = sh.part[rr * 2][c] + sh.part[rr * 2 + 1][c] + p.ba[c];
        sh.qbls[rr][c] = (short)f2b(qv);
    }
    __syncthreads();
    // scores: wave (r, sg); lane owns s = sg*64+lane, full-d accumulation
    {
        const int sg = wave & 1;
        const int s = sg * 64 + lane;
        const unsigned char* kb = p.kp8 + (size_t)(b0 + r) * (S_ * D_);
        float acc = 0.f;
        #pragma unroll 2
        for (int g = 0; g < 32; ++g) {
            uint4 kw = *(const uint4*)(kb + ((size_t)g * 128 + s) * 16);
            const short* qg = &sh.qbls[r][g * 16];
            const short* vg = p.vab + g * 16;
            s16x8 q0 = *(const s16x8*)(qg), q1 = *(const s16x8*)(qg + 8);
            s16x8 v0 = *(const s16x8*)(vg), v1 = *(const s16x8*)(vg + 8);
            f32x4 ka = fp8x4_dec(kw.x), kb4 = fp8x4_dec(kw.y);
            f32x4 kc = fp8x4_dec(kw.z), kd = fp8x4_dec(kw.w);
            #pragma unroll
            for (int j = 0; j < 4; ++j) {
                acc += tanh_pade(b2f((unsigned short)q0[j])     + ka[j])  * b2f((unsigned short)v0[j]);
                acc += tanh_pade(b2f((unsigned short)q0[4 + j]) + kb4[j]) * b2f((unsigned short)v0[4 + j]);
                acc += tanh_pade(b2f((unsigned short)q1[j])     + kc[j])  * b2f((unsigned short)v1[j]);
                acc += tanh_pade(b2f((unsigned short)q1[4 + j]) + kd[j])  * b2f((unsigned short)v1[4 + j]);
            }
        }
        sh.scp[wave][lane] = acc;
    }
    __syncthreads();
    // softmax: wave 2r handles row r
    if ((wave & 1) == 0) {
        const float bvv = p.bv[0];
        float v0 = sh.scp[wave][lane] + bvv;         // s = lane
        float v1 = sh.scp[wave + 1][lane] + bvv;     // s = lane + 64
        float m = fmaxf(v0, v1);
        #pragma unroll
        for (int o = 32; o >= 1; o >>= 1) m = fmaxf(m, __shfl_xor(m, o));
        float e0 = __expf(v0 - m), e1 = __expf(v1 - m);
        float su = e0 + e1;
        #pragma unroll
        for (int o = 32; o >= 1; o >>= 1) su += __shfl_xor(su, o);
        float inv = rcp_f(su);
        float w0 = e0 * inv, w1 = e1 * inv;
        sh.wbuf[r][lane] = w0; sh.wbuf[r][lane + 64] = w1;
        float* ao = p.out_attn + ((size_t)(b0 + r) * T_ + step) * S_;
        ao[lane] = w0; ao[lane + 64] = w1;
    }
    __syncthreads();
    // ctx partials: wave (r, sg) covers 64 s, lane owns 8 dims
    {
        const int sg = wave & 1;
        const int d0 = lane * 8;
        f32x4 aA = {0.f,0.f,0.f,0.f}, aB = {0.f,0.f,0.f,0.f};
        const unsigned char* eb = p.ea8 + (size_t)(b0 + r) * S_ * D_ + d0;
        #pragma unroll 4
        for (int i = 0; i < 64; ++i) {
            int s = sg * 64 + i;
            float wv = sh.wbuf[r][s];
            uint2 ev = *(const uint2*)(eb + (size_t)s * D_);
            f32x4 ex = fp8x4_dec(ev.x), ey = fp8x4_dec(ev.y);
            #pragma unroll
            for (int j = 0; j < 4; ++j) aA[j] += wv * ex[j];
            #pragma unroll
            for (int j = 0; j < 4; ++j) aB[j] += wv * ey[j];
        }
        *(f32x4*)&sh.part[wave][d0]     = aA;
        *(f32x4*)&sh.part[wave][d0 + 4] = aB;
    }
    __syncthreads();
    {
        int dd = t * 2;
        #pragma unroll
        for (int rr = 0; rr < 2; ++rr) {
            float v0 = sh.part[rr * 2][dd]     + sh.part[rr * 2 + 1][dd];
            float v1 = sh.part[rr * 2][dd + 1] + sh.part[rr * 2 + 1][dd + 1];
            short2 o2; o2.x = (short)f2b(v0); o2.y = (short)f2b(v1);
            *(short2*)(p.ctxb + (size_t)(b0 + rr) * D_ + dd) = o2;
        }
    }
}

// ---------------- pgate full-K (128x64 tile, K=1024): gp = xeh @ WehT^T + bcat -> bf16 ------------
// 128 blocks: m0 in {0,128,256,384}, n0 covers 2048 cols
__device__ __forceinline__ void pgate_full(const P& p, PG2& sh, int bid2)
{
    const int t = threadIdx.x, lane = t & 63, wave = t >> 6;
    const int lrow = lane & 15, kq = lane >> 4;
    const int m0 = (bid2 >> 5) * 128, n0 = (bid2 & 31) * 64;
    f32x4 acc[2][4] = {};
    for (int k0 = 0; k0 < 1024; k0 += 64) {
        s16x8 va[4], vb[2];
        #pragma unroll
        for (int r = 0; r < 4; ++r) {
            int idx = r * 256 + t, row = idx >> 3, seg = idx & 7;
            va[r] = *(const s16x8*)(p.xeh + (size_t)(m0 + row) * 1024 + k0 + seg * 8);
        }
        #pragma unroll
        for (int r = 0; r < 2; ++r) {
            int idx = r * 256 + t, row = idx >> 3, seg = idx & 7;
            vb[r] = *(const s16x8*)(p.WehT + (size_t)(n0 + row) * 1024 + k0 + seg * 8);
        }
        __syncthreads();
        #pragma unroll
        for (int r = 0; r < 4; ++r) {
            int idx = r * 256 + t, row = idx >> 3, seg = idx & 7;
            *(s16x8*)(&sh.As[row][seg * 8]) = va[r];
        }
        #pragma unroll
        for (int r = 0; r < 2; ++r) {
            int idx = r * 256 + t, row = idx >> 3, seg = idx & 7;
            *(s16x8*)(&sh.Bs[row][seg * 8]) = vb[r];
        }
        __syncthreads();
        #pragma unroll
        for (int kk = 0; kk < 64; kk += 32) {
            s16x8 af[2], bf[4];
            af[0] = *(const s16x8*)(&sh.As[wave * 32 + lrow][kk + kq * 8]);
            af[1] = *(const s16x8*)(&sh.As[wave * 32 + 16 + lrow][kk + kq * 8]);
            #pragma unroll
            for (int f = 0; f < 4; ++f)
                bf[f] = *(const s16x8*)(&sh.Bs[f * 16 + lrow][kk + kq * 8]);
            #pragma unroll
            for (int m2 = 0; m2 < 2; ++m2)
                #pragma unroll
                for (int n2 = 0; n2 < 4; ++n2)
                    acc[m2][n2] = __builtin_amdgcn_mfma_f32_16x16x32_bf16(af[m2], bf[n2], acc[m2][n2], 0, 0, 0);
        }
    }
    #pragma unroll
    for (int m2 = 0; m2 < 2; ++m2)
        #pragma unroll
        for (int n2 = 0; n2 < 4; ++n2) {
            int col = n0 + n2 * 16 + lrow;
            float bvv = p.bcat[col];
            #pragma unroll
            for (int j = 0; j < 4; ++j) {
                int row = m0 + wave * 32 + m2 * 16 + kq * 4 + j;
                p.gp[(size_t)row * 2048 + col] = (short)f2b(acc[m2][n2][j] + bvv);
            }
        }
}

// ---------------- out GEMM (64 rows, N=128, K=512) + fused log_softmax ----------------
__device__ __forceinline__ void out_phase(const P& p, OutS& sh, int obid, int step)
{
    const int t = threadIdx.x, lane = t & 63, wave = t >> 6;
    const int lrow = lane & 15, kq = lane >> 4;
    const int srow = t >> 3, sseg = t & 7;
    const int m0 = obid * 64;
    f32x4 acc[8] = {};
    for (int k0 = 0; k0 < 512; k0 += 64) {
        s16x8 va0 = *(const s16x8*)(p.h2bf + (size_t)(m0 + srow) * 512 + k0 + sseg * 8);
        s16x8 va1 = *(const s16x8*)(p.h2bf + (size_t)(m0 + srow + 32) * 512 + k0 + sseg * 8);
        s16x8 vb[4];
        #pragma unroll
        for (int p4 = 0; p4 < 4; ++p4)
            vb[p4] = *(const s16x8*)(p.WoutT + (size_t)(srow + p4 * 32) * 512 + k0 + sseg * 8);
        __syncthreads();
        *(s16x8*)(&sh.As[srow][sseg * 8]) = va0;
        *(s16x8*)(&sh.As[srow + 32][sseg * 8]) = va1;
        #pragma unroll
        for (int p4 = 0; p4 < 4; ++p4) *(s16x8*)(&sh.Bs[srow + p4 * 32][sseg * 8]) = vb[p4];
        __syncthreads();
        #pragma unroll
        for (int kk = 0; kk < 64; kk += 32) {
            s16x8 a = *(const s16x8*)(&sh.As[wave * 16 + lrow][kk + kq * 8]);
            #pragma unroll
            for (int f = 0; f < 8; ++f) {
                s16x8 b = *(const s16x8*)(&sh.Bs[f * 16 + lrow][kk + kq * 8]);
                acc[f] = __builtin_amdgcn_mfma_f32_16x16x32_bf16(a, b, acc[f], 0, 0, 0);
            }
        }
    }
    float colb[8];
    #pragma unroll
    for (int f = 0; f < 8; ++f) colb[f] = p.bout[f * 16 + lrow];
    #pragma unroll
    for (int j = 0; j < 4; ++j) {
        float v[8]; float mx = -1e30f;
        #pragma unroll
        for (int f = 0; f < 8; ++f) { v[f] = acc[f][j] + colb[f]; mx = fmaxf(mx, v[f]); }
        #pragma unroll
        for (int o = 1; o < 16; o <<= 1) mx = fmaxf(mx, __shfl_xor(mx, o));
        float sum = 0.f;
        #pragma unroll
        for (int f = 0; f < 8; ++f) sum += __expf(v[f] - mx);
        #pragma unroll
        for (int o = 1; o < 16; o <<= 1) sum += __shfl_xor(sum, o);
        float lse = mx + __logf(sum);
        int row = m0 + wave * 16 + kq * 4 + j;
        float* orow = p.out_logits + ((size_t)row * T_ + step) * V_;
        #pragma unroll
        for (int f = 0; f < 8; ++f) orow[f * 16 + lrow] = v[f] - lse;
    }
}

// ---------------- fgate (64x64 tile, K=512 ctx) + gp(read) + fused LSTM ----------------
__global__ __launch_bounds__(256, 2) void kB(P p, int step)
{
    __shared__ GateS sh;
    const int t = threadIdx.x, lane = t & 63, wave = t >> 6;
    const int wr = wave >> 1, wc = wave & 1;
    const int lrow = lane & 15, kq = lane >> 4;
    const int srow = t >> 3, sseg = t & 7;
    const int bid = blockIdx.x;
    const int m0 = (bid >> 5) * 64, n0 = (bid & 31) * 64;
    f32x4 acc[2][2] = {};
    for (int k0 = 0; k0 < 512; k0 += 64) {
        s16x8 va0 = *(const s16x8*)(p.ctxb + (size_t)(m0 + srow) * 512 + k0 + sseg * 8);
        s16x8 va1 = *(const s16x8*)(p.ctxb + (size_t)(m0 + srow + 32) * 512 + k0 + sseg * 8);
        s16x8 vb0 = *(const s16x8*)(p.WctxT + (size_t)(n0 + srow) * 512 + k0 + sseg * 8);
        s16x8 vb1 = *(const s16x8*)(p.WctxT + (size_t)(n0 + srow + 32) * 512 + k0 + sseg * 8);
        __syncthreads();
        *(s16x8*)(&sh.As[srow][sseg * 8]) = va0;
        *(s16x8*)(&sh.As[srow + 32][sseg * 8]) = va1;
        *(s16x8*)(&sh.Bs[srow][sseg * 8]) = vb0;
        *(s16x8*)(&sh.Bs[srow + 32][sseg * 8]) = vb1;
        __syncthreads();
        #pragma unroll
        for (int kk = 0; kk < 64; kk += 32) {
            s16x8 af0 = *(const s16x8*)(&sh.As[wr * 32 + lrow][kk + kq * 8]);
            s16x8 af1 = *(const s16x8*)(&sh.As[wr * 32 + 16 + lrow][kk + kq * 8]);
            s16x8 bf0 = *(const s16x8*)(&sh.Bs[wc * 32 + lrow][kk + kq * 8]);
            s16x8 bf1 = *(const s16x8*)(&sh.Bs[wc * 32 + 16 + lrow][kk + kq * 8]);
            acc[0][0] = __builtin_amdgcn_mfma_f32_16x16x32_bf16(af0, bf0, acc[0][0], 0, 0, 0);
            acc[0][1] = __builtin_amdgcn_mfma_f32_16x16x32_bf16(af0, bf1, acc[0][1], 0, 0, 0);
            acc[1][0] = __builtin_amdgcn_mfma_f32_16x16x32_bf16(af1, bf0, acc[1][0], 0, 0, 0);
            acc[1][1] = __builtin_amdgcn_mfma_f32_16x16x32_bf16(af1, bf1, acc[1][1], 0, 0, 0);
        }
    }
    #pragma unroll
    for (int m2 = 0; m2 < 2; ++m2)
        #pragma unroll
        for (int n2 = 0; n2 < 2; ++n2) {
            int cl = wc * 32 + n2 * 16 + lrow;
            #pragma unroll
            for (int j = 0; j < 4; ++j) {
                int rl = wr * 32 + m2 * 16 + kq * 4 + j;
                sh.gt[rl][cl] = acc[m2][n2][j]
                              + b2f((unsigned short)p.gp[(size_t)(m0 + rl) * 2048 + n0 + cl]);
            }
        }
    __syncthreads();
    // LSTM epilogue: thread -> (row, dim-pair), packed 4B stores
    const int dp = t & 7, rr = t >> 3;
    #pragma unroll
    for (int pass = 0; pass < 2; ++pass) {
        int row = pass * 32 + rr;
        int b = m0 + row;
        int dl0 = dp * 2;
        float gi0 = sh.gt[row][dl0 * 4 + 0], gf0 = sh.gt[row][dl0 * 4 + 1];
        float gg0 = sh.gt[row][dl0 * 4 + 2], go0 = sh.gt[row][dl0 * 4 + 3];
        float gi1 = sh.gt[row][dl0 * 4 + 4], gf1 = sh.gt[row][dl0 * 4 + 5];
        float gg1 = sh.gt[row][dl0 * 4 + 6], go1 = sh.gt[row][dl0 * 4 + 7];
        int d = (n0 >> 2) + dl0;
        float2 cv = *(const float2*)(p.cst + (size_t)b * 512 + d);
        float c20 = sigm(gf0) * cv.x + sigm(gi0) * tanh_fast(gg0);
        float h20 = sigm(go0) * tanh_fast(c20);
        float c21 = sigm(gf1) * cv.y + sigm(gi1) * tanh_fast(gg1);
        float h21 = sigm(go1) * tanh_fast(c21);
        float2 cw; cw.x = c20; cw.y = c21;
        *(float2*)(p.cst + (size_t)b * 512 + d) = cw;
        unsigned hcp = (unsigned)f2b(h20 + c20) | ((unsigned)f2b(h21 + c21) << 16);
        unsigned h2p = (unsigned)f2b(h20) | ((unsigned)f2b(h21) << 16);
        *(unsigned*)(p.hcbf + (size_t)b * 512 + d) = hcp;
        *(unsigned*)(p.h2bf + (size_t)b * 512 + d) = h2p;
        *(unsigned*)(p.xeh + (size_t)b * 1024 + 512 + d) = h2p;
        int tok = p.target[b * T_ + step];
        unsigned ep = (unsigned)f2b(p.E[(size_t)tok * 512 + d])
                    | ((unsigned)f2b(p.E[(size_t)tok * 512 + d + 1]) << 16);
        *(unsigned*)(p.xeh + (size_t)b * 1024 + d) = ep;
    }
}

// ===== D1: attn+q (0..255, 2 rows each) | pgate (256..383) | out_{t-1} (384..391) =====
__global__ __launch_bounds__(256, 2) void kD1(P p, int step)
{
    __shared__ SharedD1 sh;
    const int bid = blockIdx.x;
    if (bid < 256)       attn2_phase(p, sh.a, bid, step);
    else if (bid < 384)  pgate_full(p, sh.pg, bid - 256);
    else if (step > 0)   out_phase(p, sh.o, bid - 384, step - 1);
}

__global__ __launch_bounds__(256, 2) void kOutLast(P p, int step)
{
    __shared__ OutS sh;
    out_phase(p, sh, blockIdx.x, step);
}

// ---------------- precompute kernels ----------------
__global__ __launch_bounds__(256)
void gemm64(const short* __restrict__ A, const short* __restrict__ Bt,
            const float* __restrict__ bias, short* __restrict__ Cp,
            int M, int N, int K)
{
    __shared__ __align__(16) short As[64][LDW];
    __shared__ __align__(16) short Bs[64][LDW];
    const int t = threadIdx.x;
    const int lane = t & 63, wave = t >> 6;
    const int wr = wave >> 1, wc = wave & 1;
    const int lrow = lane & 15, kq = lane >> 4;
    const int m0 = blockIdx.y * 64, n0 = blockIdx.x * 64;
    const int srow = t >> 3, sseg = t & 7;
    f32x4 acc[2][2] = {};
    for (int k0 = 0; k0 < K; k0 += 64) {
        s16x8 va0 = *(const s16x8*)(A + (size_t)(m0 + srow) * K + k0 + sseg * 8);
        s16x8 va1 = *(const s16x8*)(A + (size_t)(m0 + srow + 32) * K + k0 + sseg * 8);
        s16x8 vb0 = *(const s16x8*)(Bt + (size_t)(n0 + srow) * K + k0 + sseg * 8);
        s16x8 vb1 = *(const s16x8*)(Bt + (size_t)(n0 + srow + 32) * K + k0 + sseg * 8);
        __syncthreads();
        *(s16x8*)(&As[srow][sseg * 8]) = va0;
        *(s16x8*)(&As[srow + 32][sseg * 8]) = va1;
        *(s16x8*)(&Bs[srow][sseg * 8]) = vb0;
        *(s16x8*)(&Bs[srow + 32][sseg * 8]) = vb1;
        __syncthreads();
        for (int kk = 0; kk < 64; kk += 32) {
            s16x8 af[2], bf[2];
            af[0] = *(const s16x8*)(&As[wr * 32 + lrow][kk + kq * 8]);
            af[1] = *(const s16x8*)(&As[wr * 32 + 16 + lrow][kk + kq * 8]);
            bf[0] = *(const s16x8*)(&Bs[wc * 32 + lrow][kk + kq * 8]);
            bf[1] = *(const s16x8*)(&Bs[wc * 32 + 16 + lrow][kk + kq * 8]);
            for (int m2 = 0; m2 < 2; ++m2)
                for (int n2 = 0; n2 < 2; ++n2)
                    acc[m2][n2] = __builtin_amdgcn_mfma_f32_16x16x32_bf16(af[m2], bf[n2], acc[m2][n2], 0, 0, 0);
        }
    }
    for (int m2 = 0; m2 < 2; ++m2)
        for (int n2 = 0; n2 < 2; ++n2) {
            int col = n0 + wc * 32 + n2 * 16 + lrow;
            float bvv = bias ? bias[col] : 0.0f;
            for (int j = 0; j < 4; ++j) {
                int row = m0 + wr * 32 + m2 * 16 + kq * 4 + j;
                Cp[(size_t)row * N + col] = (short)f2b(acc[m2][n2][j] + bvv);
            }
        }
}

__global__ __launch_bounds__(256)
void transpose_kp8(const short* __restrict__ in, unsigned char* __restrict__ out)
{
    const int b = blockIdx.x, t = threadIdx.x;
    const size_t ibase = (size_t)b * (S_ * D_);
    for (int k = t; k < 32 * S_; k += 256) {
        int g = k >> 7, s = k & 127;
        const short* src = in + ibase + (size_t)s * D_ + g * 16;
        unsigned w[4];
        #pragma unroll
        for (int q4 = 0; q4 < 4; ++q4) {
            w[q4] = pk_fp8(b2f((unsigned short)src[q4 * 4 + 0]), b2f((unsigned short)src[q4 * 4 + 1]),
                           b2f((unsigned short)src[q4 * 4 + 2]), b2f((unsigned short)src[q4 * 4 + 3]));
        }
        uint4 o; o.x = w[0]; o.y = w[1]; o.z = w[2]; o.w = w[3];
        *(uint4*)(out + ibase + ((size_t)g * S_ + s) * 16) = o;
    }
}

__global__ __launch_bounds__(256)
void cast_fp8_v4(const float* __restrict__ in, unsigned char* __restrict__ out, int n4)
{
    int i = blockIdx.x * 256 + threadIdx.x;
    int stride = gridDim.x * 256;
    for (; i < n4; i += stride) {
        f32x4 v = ((const f32x4*)in)[i];
        ((unsigned*)out)[i] = pk_fp8(v[0], v[1], v[2], v[3]);
    }
}

__global__ __launch_bounds__(256)
void init_state(const float* __restrict__ e_h, const float* __restrict__ e_c,
                float* __restrict__ c, short* __restrict__ hcbf,
                short* __restrict__ xeh, const float* __restrict__ E)
{
    int gid = blockIdx.x * 256 + threadIdx.x;
    int b = gid >> 9, d = gid & 511;
    float h0 = e_h[gid], c0 = e_c[gid];
    c[gid] = c0;
    hcbf[gid] = (short)f2b(h0 + c0);
    xeh[(size_t)b * 1024 + 512 + d] = (short)f2b(h0);
    xeh[(size_t)b * 1024 + d] = (short)f2b(E[d]);   // token 0 (SOS)
}

__global__ __launch_bounds__(256)
void transpose_cast(const float* __restrict__ in, short* __restrict__ out,
                    int N, int ostride, int koff, int gate_perm)
{
    __shared__ float tile[64][65];
    int t = threadIdx.x;
    int n0 = blockIdx.x * 64, k0 = blockIdx.y * 64;
    int cc = t & 63, r4 = t >> 6;
    for (int i = 0; i < 16; ++i) {
        int r = i * 4 + r4;
        tile[r][cc] = in[(size_t)(k0 + r) * N + n0 + cc];
    }
    __syncthreads();
    for (int i = 0; i < 16; ++i) {
        int nr = i * 4 + r4;
        int ng = n0 + nr;
        int np = gate_perm ? ((ng & 511) * 4 + (ng >> 9)) : ng;
        out[(size_t)np * ostride + koff + k0 + cc] = (short)f2b(tile[cc][nr]);
    }
}

__global__ __launch_bounds__(256)
void cast_bf16_v4(const float* __restrict__ in, short* __restrict__ out, int n4)
{
    int i = blockIdx.x * 256 + threadIdx.x;
    int stride = gridDim.x * 256;
    for (; i < n4; i += stride) {
        f32x4 v = ((const f32x4*)in)[i];
        s16x4 o;
        for (int j = 0; j < 4; ++j) o[j] = (short)f2b(v[j]);
        ((s16x4*)out)[i] = o;
    }
}

__global__ __launch_bounds__(256)
void make_bcat(const float* __restrict__ b_ih, const float* __restrict__ b_hh, float* __restrict__ bcat)
{
    int i = blockIdx.x * 256 + threadIdx.x;
    if (i < 2048) {
        int np = (i & 511) * 4 + (i >> 9);
        bcat[np] = b_ih[i] + b_hh[i];
    }
}

extern "C" void kernel_launch(void* const* d_in, const int* in_sizes, int n_in,
                              void* d_out, int out_size, void* d_ws, size_t ws_size,
                              hipStream_t stream)
{
    const float* e_all  = (const float*)d_in[0];
    const float* e_h    = (const float*)d_in[1];
    const float* e_c    = (const float*)d_in[2];
    const int*   target = (const int*)d_in[3];
    const float* E      = (const float*)d_in[4];
    const float* Wa     = (const float*)d_in[5];
    const float* ba     = (const float*)d_in[6];
    const float* Ua     = (const float*)d_in[7];
    const float* bu     = (const float*)d_in[8];
    const float* Va     = (const float*)d_in[9];
    const float* bv     = (const float*)d_in[10];
    const float* W_ih   = (const float*)d_in[11];
    const float* b_ih   = (const float*)d_in[12];
    const float* W_hh   = (const float*)d_in[13];
    const float* b_hh   = (const float*)d_in[14];
    const float* W_out  = (const float*)d_in[15];
    const float* b_out  = (const float*)d_in[16];

    char* ws = (char*)d_ws;
    size_t off = 0;
    auto alloc = [&](size_t bytes) { void* p = ws + off; off += (bytes + 255) & ~255ull; return p; };
    short* ealb  = (short*)alloc((size_t)B_ * S_ * D_ * 2);
    short* kpb   = (short*)alloc((size_t)B_ * S_ * D_ * 2);
    unsigned char* kp8 = (unsigned char*)alloc((size_t)B_ * S_ * D_);
    unsigned char* ea8 = (unsigned char*)alloc((size_t)B_ * S_ * D_);
    short* Wab   = (short*)alloc((size_t)D_ * D_ * 2);           // Wa bf16, [k][col]
    short* UaT   = (short*)alloc((size_t)D_ * D_ * 2);
    short* WehT  = (short*)alloc((size_t)2048 * 1024 * 2);
    short* WctxT = (short*)alloc((size_t)2048 * 512 * 2);
    short* WoutT = (short*)alloc((size_t)V_ * D_ * 2);
    float* bcat  = (float*)alloc(2048 * 4);
    short* vab   = (short*)alloc((size_t)D_ * 2);
    short* xeh   = (short*)alloc((size_t)B_ * 1024 * 2);
    short* ctxb  = (short*)alloc((size_t)B_ * D_ * 2);
    short* gp    = (short*)alloc((size_t)B_ * 2048 * 2);
    short* hcbf  = (short*)alloc((size_t)B_ * D_ * 2);
    short* h2bf  = (short*)alloc((size_t)B_ * D_ * 2);
    float* cst   = (float*)alloc((size_t)B_ * D_ * 4);
    if (off > ws_size) return;

    float* out_logits = (float*)d_out;                        // [B,T,V]
    float* out_attn   = (float*)d_out + (size_t)B_ * T_ * V_; // [B,T,S]

    // ---- precompute ----
    cast_bf16_v4<<<4096, 256, 0, stream>>>(e_all, ealb, B_ * S_ * D_ / 4);
    cast_fp8_v4<<<4096, 256, 0, stream>>>(e_all, ea8, B_ * S_ * D_ / 4);
    cast_bf16_v4<<<1,    256, 0, stream>>>(Va, vab, D_ / 4);
    cast_bf16_v4<<<256,  256, 0, stream>>>(Wa, Wab, D_ * D_ / 4);
    transpose_cast<<<dim3(8, 8),  256, 0, stream>>>(Ua,  UaT,  512,  512, 0, 0);
    transpose_cast<<<dim3(32, 8), 256, 0, stream>>>(W_ih,              WehT,  2048, 1024, 0,   1);
    transpose_cast<<<dim3(32, 8), 256, 0, stream>>>(W_ih + 512 * 2048, WctxT, 2048, 512,  0,   1);
    transpose_cast<<<dim3(32, 8), 256, 0, stream>>>(W_hh,              WehT,  2048, 1024, 512, 1);
    transpose_cast<<<dim3(2, 8),  256, 0, stream>>>(W_out, WoutT, 128, 512, 0, 0);
    make_bcat<<<8, 256, 0, stream>>>(b_ih, b_hh, bcat);
    gemm64<<<dim3(8, 1024), 256, 0, stream>>>(ealb, UaT, bu, kpb, B_ * S_, 512, 512);
    transpose_kp8<<<512, 256, 0, stream>>>(kpb, kp8);
    init_state<<<1024, 256, 0, stream>>>(e_h, e_c, cst, hcbf, xeh, E);

    P pp;
    pp.target = target; pp.E = E; pp.bv = bv; pp.ba = ba; pp.bout = b_out; pp.bcat = bcat;
    pp.vab = vab; pp.ea8 = ea8; pp.kp8 = kp8;
    pp.Wab = Wab; pp.WehT = WehT; pp.WctxT = WctxT; pp.WoutT = WoutT;
    pp.ctxb = ctxb; pp.gp = gp;
    pp.cst = cst; pp.hcbf = hcbf; pp.h2bf = h2bf; pp.xeh = xeh;
    pp.out_logits = out_logits; pp.out_attn = out_attn;

    // ---- sequential decode: 2 dispatches per step ----
    // D1(t): attn+q (needs hcbf from kB(t-1)) | pgate(t) (needs xeh from kB(t-1)) | out(t-1)
    // D2(t): fgate+LSTM (needs ctxb, gp from D1(t))
    for (int t = 0; t < T_; ++t) {
        kD1<<<392, 256, 0, stream>>>(pp, t);
        kB<<<256, 256, 0, stream>>>(pp, t);
    }
    kOutLast<<<8, 256, 0, stream>>>(pp, T_ - 1);
    (void)n_in; (void)in_sizes; (void)out_size;
}

// Round 16
// 6286.801 us; speedup vs baseline: 4.8012x; 1.2445x over previous
//
#include <hip/hip_runtime.h>

#define B_ 512
#define S_ 128
#define T_ 128
#define D_ 512
#define V_ 128
#define LDW 72   // 144B row stride -> 2-way LDS bank aliasing on ds_read_b128 (free)

typedef __attribute__((ext_vector_type(8))) short s16x8;
typedef __attribute__((ext_vector_type(4))) short s16x4;
typedef __attribute__((ext_vector_type(4))) float f32x4;

__device__ __forceinline__ float b2f(unsigned short h) {
    union { unsigned int u; float f; } x; x.u = ((unsigned int)h) << 16; return x.f;
}
__device__ __forceinline__ unsigned short f2b(float f) {
    union { float f; unsigned int u; } x; x.f = f;
    unsigned int u = x.u; u += 0x7FFFu + ((u >> 16) & 1u);
    return (unsigned short)(u >> 16);
}
#if __has_builtin(__builtin_amdgcn_rcpf)
__device__ __forceinline__ float rcp_f(float x) { return __builtin_amdgcn_rcpf(x); }
#else
__device__ __forceinline__ float rcp_f(float x) { return 1.0f / x; }
#endif
__device__ __forceinline__ float sigm(float x) { return rcp_f(1.0f + __expf(-x)); }
__device__ __forceinline__ float tanh_fast(float x) {
    float e = __expf(2.0f * fabsf(x));          // e^{2|x|}; inf -> rcp=0 -> 1.0
    float r = 1.0f - 2.0f * rcp_f(e + 1.0f);
    return copysignf(r, x);
}
// Pade[3/2] tanh: max |err| ~7e-4 with clamp; 1 rcp, no exp.
__device__ __forceinline__ float tanh_pade(float x) {
    float t = x * x;
    float num = x * fmaf(t, 105.0f + t, 945.0f);
    float den = fmaf(t, fmaf(t, 15.0f, 420.0f), 945.0f);
    float r = num * rcp_f(den);
    return fminf(1.0f, fmaxf(-1.0f, r));
}

// ---------------- fp8 (OCP e4m3) encode/decode ----------------
#if __has_builtin(__builtin_amdgcn_cvt_f32_fp8)
__device__ __forceinline__ f32x4 fp8x4_dec(unsigned w) {
    f32x4 r;
    r[0] = __builtin_amdgcn_cvt_f32_fp8(w, 0);
    r[1] = __builtin_amdgcn_cvt_f32_fp8(w, 1);
    r[2] = __builtin_amdgcn_cvt_f32_fp8(w, 2);
    r[3] = __builtin_amdgcn_cvt_f32_fp8(w, 3);
    return r;
}
#else
__device__ __forceinline__ float fp8_dec_sw(unsigned w, int j) {
    unsigned char v = (w >> (8 * j)) & 0xFF;
    unsigned s = v >> 7, e = (v >> 3) & 0xF, m = v & 7;
    float r = (e == 0) ? ldexpf((float)m, -9) : ldexpf((float)(8 + m), (int)e - 10);
    return s ? -r : r;
}
__device__ __forceinline__ f32x4 fp8x4_dec(unsigned w) {
    f32x4 r;
    r[0] = fp8_dec_sw(w, 0); r[1] = fp8_dec_sw(w, 1);
    r[2] = fp8_dec_sw(w, 2); r[3] = fp8_dec_sw(w, 3);
    return r;
}
#endif

#if __has_builtin(__builtin_amdgcn_cvt_pk_fp8_f32)
__device__ __forceinline__ unsigned pk_fp8(float a, float b, float c, float d) {
    int r = 0;
    r = __builtin_amdgcn_cvt_pk_fp8_f32(a, b, r, false);
    r = __builtin_amdgcn_cvt_pk_fp8_f32(c, d, r, true);
    return (unsigned)r;
}
#else
__device__ __forceinline__ unsigned char f32_to_fp8_sw(float x) {
    unsigned s = x < 0.f ? 0x80u : 0u; float a = fabsf(x);
    if (a != a) return (unsigned char)(s | 0x7F);
    if (a >= 448.f) return (unsigned char)(s | 0x7E);
    if (a < 0.001953125f) { int m = (int)rintf(a * 512.0f); return (unsigned char)(s | (m > 7 ? 0x08 : m)); }
    int e; float fr = frexpf(a, &e);
    int m = (int)rintf(fr * 16.0f - 8.0f);
    int ee = e - 1 + 7;
    if (m == 8) { m = 0; ee += 1; }
    if (ee <= 0) { int mm = (int)rintf(a * 512.f); return (unsigned char)(s | (mm > 7 ? 0x08 : mm)); }
    if (ee >= 16) return (unsigned char)(s | 0x7E);
    return (unsigned char)(s | (ee << 3) | m);
}
__device__ __forceinline__ unsigned pk_fp8(float a, float b, float c, float d) {
    return (unsigned)f32_to_fp8_sw(a) | ((unsigned)f32_to_fp8_sw(b) << 8)
         | ((unsigned)f32_to_fp8_sw(c) << 16) | ((unsigned)f32_to_fp8_sw(d) << 24);
}
#endif

struct P {
    const int* target;
    const float* E; const float* bv; const float* ba; const float* bout;
    const short* vab;
    const unsigned char* ea8; const unsigned char* kp8;
    const short* WaT; const short* WehT; const short* WctxT; const short* WoutT;
    const float* bcat;
    short* qbf; short* xeh; short* ctxb; short* gpA; short* gpB;
    short* hcbf; short* h2bf; float* cst;
    float* out_logits; float* out_attn;
};

struct AttnS { float scp[4][64]; float wbuf[S_]; float cpart[4][D_]; };
struct OutS  { short As[64][LDW]; short Bs[128][LDW]; };
struct PG2   { short As[128][LDW]; short Bs[64][LDW]; };
struct GateS { short As[64][LDW]; short Bs[64][LDW]; float gt[64][65]; };
union SharedC { OutS o; PG2 g; };

// ---------------- attention: fp8 K/e_all, lane-per-s coalesced scores + wave0 softmax + ctx --------
// kp8 layout: [b][g=d/16][s][16B] -> lane l (s=l) reads 16B; 64 lanes = 1KB contiguous per instr
__global__ __launch_bounds__(256, 2) void kA(P p, int step)
{
    __shared__ AttnS sh;
    const int b = blockIdx.x;
    const int t = threadIdx.x, lane = t & 63, wave = t >> 6;
    {
        const int sg = wave & 1, dh = wave >> 1;     // s-group, d-half
        const int s = sg * 64 + lane;
        const unsigned char* kb = p.kp8 + (size_t)b * (S_ * D_);
        const short* qv = p.qbf + (size_t)b * D_;
        float acc = 0.f;
        #pragma unroll 4
        for (int i = 0; i < 16; ++i) {
            int g = dh * 16 + i;
            uint4 kw = *(const uint4*)(kb + ((size_t)g * 128 + s) * 16);
            const short* qg = qv + g * 16;
            const short* vg = p.vab + g * 16;
            s16x8 q0 = *(const s16x8*)(qg), q1 = *(const s16x8*)(qg + 8);
            s16x8 v0 = *(const s16x8*)(vg), v1 = *(const s16x8*)(vg + 8);
            f32x4 ka = fp8x4_dec(kw.x), kb4 = fp8x4_dec(kw.y);
            f32x4 kc = fp8x4_dec(kw.z), kd = fp8x4_dec(kw.w);
            #pragma unroll
            for (int j = 0; j < 4; ++j) {
                acc += tanh_pade(b2f((unsigned short)q0[j])     + ka[j])  * b2f((unsigned short)v0[j]);
                acc += tanh_pade(b2f((unsigned short)q0[4 + j]) + kb4[j]) * b2f((unsigned short)v0[4 + j]);
                acc += tanh_pade(b2f((unsigned short)q1[j])     + kc[j])  * b2f((unsigned short)v1[j]);
                acc += tanh_pade(b2f((unsigned short)q1[4 + j]) + kd[j])  * b2f((unsigned short)v1[4 + j]);
            }
        }
        sh.scp[wave][lane] = acc;
    }
    __syncthreads();
    if (wave == 0) {
        const float bvv = p.bv[0];
        float v0 = sh.scp[0][lane] + sh.scp[2][lane] + bvv;   // s = lane
        float v1 = sh.scp[1][lane] + sh.scp[3][lane] + bvv;   // s = lane + 64
        float m = fmaxf(v0, v1);
        #pragma unroll
        for (int o = 32; o >= 1; o >>= 1) m = fmaxf(m, __shfl_xor(m, o));
        float e0 = __expf(v0 - m), e1 = __expf(v1 - m);
        float su = e0 + e1;
        #pragma unroll
        for (int o = 32; o >= 1; o >>= 1) su += __shfl_xor(su, o);
        float inv = rcp_f(su);
        float w0 = e0 * inv, w1 = e1 * inv;
        sh.wbuf[lane] = w0; sh.wbuf[lane + 64] = w1;
        float* ao = p.out_attn + ((size_t)b * T_ + step) * S_;
        ao[lane] = w0; ao[lane + 64] = w1;
    }
    __syncthreads();
    {
        const int d0 = lane * 8;
        f32x4 aA = {0.f,0.f,0.f,0.f}, aB = {0.f,0.f,0.f,0.f};
        const unsigned char* eb = p.ea8 + (size_t)b * S_ * D_ + d0;
        #pragma unroll 4
        for (int i = 0; i < 32; ++i) {
            int s = wave * 32 + i;
            float wv = sh.wbuf[s];
            uint2 ev = *(const uint2*)(eb + (size_t)s * D_);
            f32x4 ex = fp8x4_dec(ev.x), ey = fp8x4_dec(ev.y);
            #pragma unroll
            for (int j = 0; j < 4; ++j) aA[j] += wv * ex[j];
            #pragma unroll
            for (int j = 0; j < 4; ++j) aB[j] += wv * ey[j];
        }
        *(f32x4*)&sh.cpart[wave][d0]     = aA;
        *(f32x4*)&sh.cpart[wave][d0 + 4] = aB;
    }
    __syncthreads();
    {
        int dd = t * 2;
        float v0 = sh.cpart[0][dd]   + sh.cpart[1][dd]   + sh.cpart[2][dd]   + sh.cpart[3][dd];
        float v1 = sh.cpart[0][dd+1] + sh.cpart[1][dd+1] + sh.cpart[2][dd+1] + sh.cpart[3][dd+1];
        short2 o2; o2.x = (short)f2b(v0); o2.y = (short)f2b(v1);
        *(short2*)(p.ctxb + (size_t)b * D_ + dd) = o2;
    }
}

// -------- partial gate GEMM 128x64 (split-K): Gp = [emb,h][koff:koff+512] @ W_eh^T (+bcat) -> bf16 --
__device__ __forceinline__ void pgate_phase(const P& p, PG2& sh, int bid2, int koff,
                                            short* __restrict__ gpp, bool addb)
{
    const int t = threadIdx.x, lane = t & 63, wave = t >> 6;
    const int lrow = lane & 15, kq = lane >> 4;
    const int m0 = (bid2 >> 5) * 128, n0 = (bid2 & 31) * 64;
    f32x4 acc[2][4] = {};
    for (int k0 = 0; k0 < 512; k0 += 64) {
        s16x8 va[4], vb[2];
        #pragma unroll
        for (int r = 0; r < 4; ++r) {
            int idx = r * 256 + t, row = idx >> 3, seg = idx & 7;
            va[r] = *(const s16x8*)(p.xeh + (size_t)(m0 + row) * 1024 + koff + k0 + seg * 8);
        }
        #pragma unroll
        for (int r = 0; r < 2; ++r) {
            int idx = r * 256 + t, row = idx >> 3, seg = idx & 7;
            vb[r] = *(const s16x8*)(p.WehT + (size_t)(n0 + row) * 1024 + koff + k0 + seg * 8);
        }
        __syncthreads();
        #pragma unroll
        for (int r = 0; r < 4; ++r) {
            int idx = r * 256 + t, row = idx >> 3, seg = idx & 7;
            *(s16x8*)(&sh.As[row][seg * 8]) = va[r];
        }
        #pragma unroll
        for (int r = 0; r < 2; ++r) {
            int idx = r * 256 + t, row = idx >> 3, seg = idx & 7;
            *(s16x8*)(&sh.Bs[row][seg * 8]) = vb[r];
        }
        __syncthreads();
        #pragma unroll
        for (int kk = 0; kk < 64; kk += 32) {
            s16x8 af[2], bf[4];
            af[0] = *(const s16x8*)(&sh.As[wave * 32 + lrow][kk + kq * 8]);
            af[1] = *(const s16x8*)(&sh.As[wave * 32 + 16 + lrow][kk + kq * 8]);
            #pragma unroll
            for (int f = 0; f < 4; ++f)
                bf[f] = *(const s16x8*)(&sh.Bs[f * 16 + lrow][kk + kq * 8]);
            #pragma unroll
            for (int m2 = 0; m2 < 2; ++m2)
                #pragma unroll
                for (int n2 = 0; n2 < 4; ++n2)
                    acc[m2][n2] = __builtin_amdgcn_mfma_f32_16x16x32_bf16(af[m2], bf[n2], acc[m2][n2], 0, 0, 0);
        }
    }
    #pragma unroll
    for (int m2 = 0; m2 < 2; ++m2)
        #pragma unroll
        for (int n2 = 0; n2 < 4; ++n2) {
            int col = n0 + n2 * 16 + lrow;
            float bvv = addb ? p.bcat[col] : 0.0f;
            #pragma unroll
            for (int j = 0; j < 4; ++j) {
                int row = m0 + wave * 32 + m2 * 16 + kq * 4 + j;
                gpp[(size_t)row * 2048 + col] = (short)f2b(acc[m2][n2][j] + bvv);
            }
        }
}

// ---------------- final gate GEMM (K=512, ctx) + GpA + GpB + fused LSTM ----------------
__global__ __launch_bounds__(256, 2) void kB(P p, int step)
{
    __shared__ GateS sh;
    const int t = threadIdx.x, lane = t & 63, wave = t >> 6;
    const int wr = wave >> 1, wc = wave & 1;
    const int lrow = lane & 15, kq = lane >> 4;
    const int srow = t >> 3, sseg = t & 7;
    const int bid = blockIdx.x;
    const int m0 = (bid >> 5) * 64, n0 = (bid & 31) * 64;
    f32x4 acc[2][2] = {};
    for (int k0 = 0; k0 < 512; k0 += 64) {
        s16x8 va0 = *(const s16x8*)(p.ctxb + (size_t)(m0 + srow) * 512 + k0 + sseg * 8);
        s16x8 va1 = *(const s16x8*)(p.ctxb + (size_t)(m0 + srow + 32) * 512 + k0 + sseg * 8);
        s16x8 vb0 = *(const s16x8*)(p.WctxT + (size_t)(n0 + srow) * 512 + k0 + sseg * 8);
        s16x8 vb1 = *(const s16x8*)(p.WctxT + (size_t)(n0 + srow + 32) * 512 + k0 + sseg * 8);
        __syncthreads();
        *(s16x8*)(&sh.As[srow][sseg * 8]) = va0;
        *(s16x8*)(&sh.As[srow + 32][sseg * 8]) = va1;
        *(s16x8*)(&sh.Bs[srow][sseg * 8]) = vb0;
        *(s16x8*)(&sh.Bs[srow + 32][sseg * 8]) = vb1;
        __syncthreads();
        #pragma unroll
        for (int kk = 0; kk < 64; kk += 32) {
            s16x8 af0 = *(const s16x8*)(&sh.As[wr * 32 + lrow][kk + kq * 8]);
            s16x8 af1 = *(const s16x8*)(&sh.As[wr * 32 + 16 + lrow][kk + kq * 8]);
            s16x8 bf0 = *(const s16x8*)(&sh.Bs[wc * 32 + lrow][kk + kq * 8]);
            s16x8 bf1 = *(const s16x8*)(&sh.Bs[wc * 32 + 16 + lrow][kk + kq * 8]);
            acc[0][0] = __builtin_amdgcn_mfma_f32_16x16x32_bf16(af0, bf0, acc[0][0], 0, 0, 0);
            acc[0][1] = __builtin_amdgcn_mfma_f32_16x16x32_bf16(af0, bf1, acc[0][1], 0, 0, 0);
            acc[1][0] = __builtin_amdgcn_mfma_f32_16x16x32_bf16(af1, bf0, acc[1][0], 0, 0, 0);
            acc[1][1] = __builtin_amdgcn_mfma_f32_16x16x32_bf16(af1, bf1, acc[1][1], 0, 0, 0);
        }
    }
    #pragma unroll
    for (int m2 = 0; m2 < 2; ++m2)
        #pragma unroll
        for (int n2 = 0; n2 < 2; ++n2) {
            int cl = wc * 32 + n2 * 16 + lrow;
            #pragma unroll
            for (int j = 0; j < 4; ++j) {
                int rl = wr * 32 + m2 * 16 + kq * 4 + j;
                size_t gidx = (size_t)(m0 + rl) * 2048 + n0 + cl;
                sh.gt[rl][cl] = acc[m2][n2][j]
                              + b2f((unsigned short)p.gpA[gidx])
                              + b2f((unsigned short)p.gpB[gidx]);
            }
        }
    __syncthreads();
    const int rl4 = t >> 4, dl = t & 15;
    #pragma unroll
    for (int pass = 0; pass < 4; ++pass) {
        int row = pass * 16 + rl4;
        int b = m0 + row;
        int d = (n0 >> 2) + dl;
        float gi = sh.gt[row][dl * 4 + 0];
        float gf = sh.gt[row][dl * 4 + 1];
        float gg = sh.gt[row][dl * 4 + 2];
        float go = sh.gt[row][dl * 4 + 3];
        float cv = p.cst[(size_t)b * D_ + d];
        float c2 = sigm(gf) * cv + sigm(gi) * tanh_fast(gg);
        float h2 = sigm(go) * tanh_fast(c2);
        p.cst[(size_t)b * D_ + d] = c2;
        p.hcbf[(size_t)b * D_ + d] = (short)f2b(h2 + c2);
        p.h2bf[(size_t)b * D_ + d] = (short)f2b(h2);
        p.xeh[(size_t)b * 1024 + 512 + d] = (short)f2b(h2);
        int tok = p.target[b * T_ + step];
        p.xeh[(size_t)b * 1024 + d] = (short)f2b(p.E[(size_t)tok * D_ + d]);
    }
}

// ---------------- q GEMM 64x32 tiles -> bf16 q ----------------
__device__ __forceinline__ void q_phase(const P& p, OutS& sh, int bid)
{
    const int t = threadIdx.x, lane = t & 63, wave = t >> 6;
    const int lrow = lane & 15, kq = lane >> 4;
    const int srow = t >> 3, sseg = t & 7;
    const int m0 = (bid >> 4) * 64, n0 = (bid & 15) * 32;
    f32x4 acc0 = {}, acc1 = {};
    for (int k0 = 0; k0 < 512; k0 += 64) {
        s16x8 va0 = *(const s16x8*)(p.hcbf + (size_t)(m0 + srow) * 512 + k0 + sseg * 8);
        s16x8 va1 = *(const s16x8*)(p.hcbf + (size_t)(m0 + srow + 32) * 512 + k0 + sseg * 8);
        int brow = n0 + (srow & 31);
        s16x8 vb0 = *(const s16x8*)(p.WaT + (size_t)brow * 512 + k0 + sseg * 8);
        __syncthreads();
        *(s16x8*)(&sh.As[srow][sseg * 8]) = va0;
        *(s16x8*)(&sh.As[srow + 32][sseg * 8]) = va1;
        if (srow < 32) *(s16x8*)(&sh.Bs[srow][sseg * 8]) = vb0;
        __syncthreads();
        #pragma unroll
        for (int kk = 0; kk < 64; kk += 32) {
            s16x8 af  = *(const s16x8*)(&sh.As[wave * 16 + lrow][kk + kq * 8]);
            s16x8 bf0 = *(const s16x8*)(&sh.Bs[lrow][kk + kq * 8]);
            s16x8 bf1 = *(const s16x8*)(&sh.Bs[16 + lrow][kk + kq * 8]);
            acc0 = __builtin_amdgcn_mfma_f32_16x16x32_bf16(af, bf0, acc0, 0, 0, 0);
            acc1 = __builtin_amdgcn_mfma_f32_16x16x32_bf16(af, bf1, acc1, 0, 0, 0);
        }
    }
    #pragma unroll
    for (int n2 = 0; n2 < 2; ++n2) {
        int col = n0 + n2 * 16 + lrow;
        float bvv = p.ba[col];
        f32x4 av = n2 ? acc1 : acc0;
        #pragma unroll
        for (int j = 0; j < 4; ++j) {
            int row = m0 + wave * 16 + kq * 4 + j;
            p.qbf[(size_t)row * 512 + col] = (short)f2b(av[j] + bvv);
        }
    }
}

// ---------------- out GEMM (M=512,N=128,K=512) + fused log_softmax ----------------
__device__ __forceinline__ void out_phase(const P& p, OutS& sh, int obid, int step)
{
    const int t = threadIdx.x, lane = t & 63, wave = t >> 6;
    const int lrow = lane & 15, kq = lane >> 4;
    const int srow = t >> 3, sseg = t & 7;
    const int m0 = obid * 64;
    f32x4 acc[8] = {};
    for (int k0 = 0; k0 < 512; k0 += 64) {
        s16x8 va0 = *(const s16x8*)(p.h2bf + (size_t)(m0 + srow) * 512 + k0 + sseg * 8);
        s16x8 va1 = *(const s16x8*)(p.h2bf + (size_t)(m0 + srow + 32) * 512 + k0 + sseg * 8);
        s16x8 vb[4];
        #pragma unroll
        for (int p4 = 0; p4 < 4; ++p4)
            vb[p4] = *(const s16x8*)(p.WoutT + (size_t)(srow + p4 * 32) * 512 + k0 + sseg * 8);
        __syncthreads();
        *(s16x8*)(&sh.As[srow][sseg * 8]) = va0;
        *(s16x8*)(&sh.As[srow + 32][sseg * 8]) = va1;
        #pragma unroll
        for (int p4 = 0; p4 < 4; ++p4) *(s16x8*)(&sh.Bs[srow + p4 * 32][sseg * 8]) = vb[p4];
        __syncthreads();
        #pragma unroll
        for (int kk = 0; kk < 64; kk += 32) {
            s16x8 a = *(const s16x8*)(&sh.As[wave * 16 + lrow][kk + kq * 8]);
            #pragma unroll
            for (int f = 0; f < 8; ++f) {
                s16x8 b = *(const s16x8*)(&sh.Bs[f * 16 + lrow][kk + kq * 8]);
                acc[f] = __builtin_amdgcn_mfma_f32_16x16x32_bf16(a, b, acc[f], 0, 0, 0);
            }
        }
    }
    float colb[8];
    #pragma unroll
    for (int f = 0; f < 8; ++f) colb[f] = p.bout[f * 16 + lrow];
    #pragma unroll
    for (int j = 0; j < 4; ++j) {
        float v[8]; float mx = -1e30f;
        #pragma unroll
        for (int f = 0; f < 8; ++f) { v[f] = acc[f][j] + colb[f]; mx = fmaxf(mx, v[f]); }
        #pragma unroll
        for (int o = 1; o < 16; o <<= 1) mx = fmaxf(mx, __shfl_xor(mx, o));
        float sum = 0.f;
        #pragma unroll
        for (int f = 0; f < 8; ++f) sum += __expf(v[f] - mx);
        #pragma unroll
        for (int o = 1; o < 16; o <<= 1) sum += __shfl_xor(sum, o);
        float lse = mx + __logf(sum);
        int row = m0 + wave * 16 + kq * 4 + j;
        float* orow = p.out_logits + ((size_t)row * T_ + step) * V_;
        #pragma unroll
        for (int f = 0; f < 8; ++f) orow[f * 16 + lrow] = v[f] - lse;
    }
}

// C: q(0..127) | pgateA(128..255) | pgateB(256..383) | out(384..391).  INIT skips out.
template<bool INIT>
__global__ __launch_bounds__(256, 2) void kC(P p, int step)
{
    __shared__ SharedC sh;
    const int bid = blockIdx.x;
    if (bid < 128)       q_phase(p, sh.o, bid);
    else if (bid < 256)  pgate_phase(p, sh.g, bid - 128, 0,   p.gpA, true);
    else if (bid < 384)  pgate_phase(p, sh.g, bid - 256, 512, p.gpB, false);
    else if (!INIT)      out_phase(p, sh.o, bid - 384, step);
}

// ---------------- precompute kernels ----------------
__global__ __launch_bounds__(256)
void gemm64(const short* __restrict__ A, const short* __restrict__ Bt,
            const float* __restrict__ bias, short* __restrict__ Cp,
            int M, int N, int K)
{
    __shared__ __align__(16) short As[64][LDW];
    __shared__ __align__(16) short Bs[64][LDW];
    const int t = threadIdx.x;
    const int lane = t & 63, wave = t >> 6;
    const int wr = wave >> 1, wc = wave & 1;
    const int lrow = lane & 15, kq = lane >> 4;
    const int m0 = blockIdx.y * 64, n0 = blockIdx.x * 64;
    const int srow = t >> 3, sseg = t & 7;
    f32x4 acc[2][2] = {};
    for (int k0 = 0; k0 < K; k0 += 64) {
        s16x8 va0 = *(const s16x8*)(A + (size_t)(m0 + srow) * K + k0 + sseg * 8);
        s16x8 va1 = *(const s16x8*)(A + (size_t)(m0 + srow + 32) * K + k0 + sseg * 8);
        s16x8 vb0 = *(const s16x8*)(Bt + (size_t)(n0 + srow) * K + k0 + sseg * 8);
        s16x8 vb1 = *(const s16x8*)(Bt + (size_t)(n0 + srow + 32) * K + k0 + sseg * 8);
        __syncthreads();
        *(s16x8*)(&As[srow][sseg * 8]) = va0;
        *(s16x8*)(&As[srow + 32][sseg * 8]) = va1;
        *(s16x8*)(&Bs[srow][sseg * 8]) = vb0;
        *(s16x8*)(&Bs[srow + 32][sseg * 8]) = vb1;
        __syncthreads();
        for (int kk = 0; kk < 64; kk += 32) {
            s16x8 af[2], bf[2];
            af[0] = *(const s16x8*)(&As[wr * 32 + lrow][kk + kq * 8]);
            af[1] = *(const s16x8*)(&As[wr * 32 + 16 + lrow][kk + kq * 8]);
            bf[0] = *(const s16x8*)(&Bs[wc * 32 + lrow][kk + kq * 8]);
            bf[1] = *(const s16x8*)(&Bs[wc * 32 + 16 + lrow][kk + kq * 8]);
            for (int m2 = 0; m2 < 2; ++m2)
                for (int n2 = 0; n2 < 2; ++n2)
                    acc[m2][n2] = __builtin_amdgcn_mfma_f32_16x16x32_bf16(af[m2], bf[n2], acc[m2][n2], 0, 0, 0);
        }
    }
    for (int m2 = 0; m2 < 2; ++m2)
        for (int n2 = 0; n2 < 2; ++n2) {
            int col = n0 + wc * 32 + n2 * 16 + lrow;
            float bvv = bias ? bias[col] : 0.0f;
            for (int j = 0; j < 4; ++j) {
                int row = m0 + wr * 32 + m2 * 16 + kq * 4 + j;
                Cp[(size_t)row * N + col] = (short)f2b(acc[m2][n2][j] + bvv);
            }
        }
}

// kpb[b][s][d] (bf16) -> kp8[b][g=d/16][s][16B] (fp8)
__global__ __launch_bounds__(256)
void transpose_kp8(const short* __restrict__ in, unsigned char* __restrict__ out)
{
    const int b = blockIdx.x, t = threadIdx.x;
    const size_t ibase = (size_t)b * (S_ * D_);
    for (int k = t; k < 32 * S_; k += 256) {
        int g = k >> 7, s = k & 127;
        const short* src = in + ibase + (size_t)s * D_ + g * 16;
        unsigned w[4];
        #pragma unroll
        for (int q4 = 0; q4 < 4; ++q4) {
            w[q4] = pk_fp8(b2f((unsigned short)src[q4 * 4 + 0]), b2f((unsigned short)src[q4 * 4 + 1]),
                           b2f((unsigned short)src[q4 * 4 + 2]), b2f((unsigned short)src[q4 * 4 + 3]));
        }
        uint4 o; o.x = w[0]; o.y = w[1]; o.z = w[2]; o.w = w[3];
        *(uint4*)(out + ibase + ((size_t)g * S_ + s) * 16) = o;
    }
}

__global__ __launch_bounds__(256)
void cast_fp8_v4(const float* __restrict__ in, unsigned char* __restrict__ out, int n4)
{
    int i = blockIdx.x * 256 + threadIdx.x;
    int stride = gridDim.x * 256;
    for (; i < n4; i += stride) {
        f32x4 v = ((const f32x4*)in)[i];
        ((unsigned*)out)[i] = pk_fp8(v[0], v[1], v[2], v[3]);
    }
}

__global__ __launch_bounds__(256)
void init_state(const float* __restrict__ e_h, const float* __restrict__ e_c,
                float* __restrict__ c, short* __restrict__ hcbf,
                short* __restrict__ xeh, const float* __restrict__ E)
{
    int gid = blockIdx.x * 256 + threadIdx.x;
    int b = gid >> 9, d = gid & 511;
    float h0 = e_h[gid], c0 = e_c[gid];
    c[gid] = c0;
    hcbf[gid] = (short)f2b(h0 + c0);
    xeh[(size_t)b * 1024 + 512 + d] = (short)f2b(h0);
    xeh[(size_t)b * 1024 + d] = (short)f2b(E[d]);   // token 0 (SOS)
}

__global__ __launch_bounds__(256)
void transpose_cast(const float* __restrict__ in, short* __restrict__ out,
                    int N, int ostride, int koff, int gate_perm)
{
    __shared__ float tile[64][65];
    int t = threadIdx.x;
    int n0 = blockIdx.x * 64, k0 = blockIdx.y * 64;
    int cc = t & 63, r4 = t >> 6;
    for (int i = 0; i < 16; ++i) {
        int r = i * 4 + r4;
        tile[r][cc] = in[(size_t)(k0 + r) * N + n0 + cc];
    }
    __syncthreads();
    for (int i = 0; i < 16; ++i) {
        int nr = i * 4 + r4;
        int ng = n0 + nr;
        int np = gate_perm ? ((ng & 511) * 4 + (ng >> 9)) : ng;
        out[(size_t)np * ostride + koff + k0 + cc] = (short)f2b(tile[cc][nr]);
    }
}

__global__ __launch_bounds__(256)
void cast_bf16_v4(const float* __restrict__ in, short* __restrict__ out, int n4)
{
    int i = blockIdx.x * 256 + threadIdx.x;
    int stride = gridDim.x * 256;
    for (; i < n4; i += stride) {
        f32x4 v = ((const f32x4*)in)[i];
        s16x4 o;
        for (int j = 0; j < 4; ++j) o[j] = (short)f2b(v[j]);
        ((s16x4*)out)[i] = o;
    }
}

__global__ __launch_bounds__(256)
void make_bcat(const float* __restrict__ b_ih, const float* __restrict__ b_hh, float* __restrict__ bcat)
{
    int i = blockIdx.x * 256 + threadIdx.x;
    if (i < 2048) {
        int np = (i & 511) * 4 + (i >> 9);
        bcat[np] = b_ih[i] + b_hh[i];
    }
}

extern "C" void kernel_launch(void* const* d_in, const int* in_sizes, int n_in,
                              void* d_out, int out_size, void* d_ws, size_t ws_size,
                              hipStream_t stream)
{
    const float* e_all  = (const float*)d_in[0];
    const float* e_h    = (const float*)d_in[1];
    const float* e_c    = (const float*)d_in[2];
    const int*   target = (const int*)d_in[3];
    const float* E      = (const float*)d_in[4];
    const float* Wa     = (const float*)d_in[5];
    const float* ba     = (const float*)d_in[6];
    const float* Ua     = (const float*)d_in[7];
    const float* bu     = (const float*)d_in[8];
    const float* Va     = (const float*)d_in[9];
    const float* bv     = (const float*)d_in[10];
    const float* W_ih   = (const float*)d_in[11];
    const float* b_ih   = (const float*)d_in[12];
    const float* W_hh   = (const float*)d_in[13];
    const float* b_hh   = (const float*)d_in[14];
    const float* W_out  = (const float*)d_in[15];
    const float* b_out  = (const float*)d_in[16];

    char* ws = (char*)d_ws;
    size_t off = 0;
    auto alloc = [&](size_t bytes) { void* p = ws + off; off += (bytes + 255) & ~255ull; return p; };
    short* ealb  = (short*)alloc((size_t)B_ * S_ * D_ * 2);
    short* kpb   = (short*)alloc((size_t)B_ * S_ * D_ * 2);          // bf16 scratch (pre-fp8)
    unsigned char* kp8 = (unsigned char*)alloc((size_t)B_ * S_ * D_); // fp8 [b][d/16][s][16]
    unsigned char* ea8 = (unsigned char*)alloc((size_t)B_ * S_ * D_); // fp8 [b][s][d]
    short* WaT   = (short*)alloc((size_t)D_ * D_ * 2);
    short* UaT   = (short*)alloc((size_t)D_ * D_ * 2);
    short* WehT  = (short*)alloc((size_t)2048 * 1024 * 2);
    short* WctxT = (short*)alloc((size_t)2048 * 512 * 2);
    short* WoutT = (short*)alloc((size_t)V_ * D_ * 2);
    float* bcat  = (float*)alloc(2048 * 4);
    short* qbf   = (short*)alloc((size_t)B_ * D_ * 2);
    short* vab   = (short*)alloc((size_t)D_ * 2);
    short* xeh   = (short*)alloc((size_t)B_ * 1024 * 2);
    short* ctxb  = (short*)alloc((size_t)B_ * D_ * 2);
    short* gpA   = (short*)alloc((size_t)B_ * 2048 * 2);
    short* gpB   = (short*)alloc((size_t)B_ * 2048 * 2);
    short* hcbf  = (short*)alloc((size_t)B_ * D_ * 2);
    short* h2bf  = (short*)alloc((size_t)B_ * D_ * 2);
    float* cst   = (float*)alloc((size_t)B_ * D_ * 4);
    if (off > ws_size) return;

    float* out_logits = (float*)d_out;                        // [B,T,V]
    float* out_attn   = (float*)d_out + (size_t)B_ * T_ * V_; // [B,T,S]

    // ---- precompute ----
    cast_bf16_v4<<<4096, 256, 0, stream>>>(e_all, ealb, B_ * S_ * D_ / 4);
    cast_fp8_v4<<<4096, 256, 0, stream>>>(e_all, ea8, B_ * S_ * D_ / 4);
    cast_bf16_v4<<<1,    256, 0, stream>>>(Va, vab, D_ / 4);
    transpose_cast<<<dim3(8, 8),  256, 0, stream>>>(Wa,  WaT,  512,  512, 0, 0);
    transpose_cast<<<dim3(8, 8),  256, 0, stream>>>(Ua,  UaT,  512,  512, 0, 0);
    transpose_cast<<<dim3(32, 8), 256, 0, stream>>>(W_ih,              WehT,  2048, 1024, 0,   1);
    transpose_cast<<<dim3(32, 8), 256, 0, stream>>>(W_ih + 512 * 2048, WctxT, 2048, 512,  0,   1);
    transpose_cast<<<dim3(32, 8), 256, 0, stream>>>(W_hh,              WehT,  2048, 1024, 512, 1);
    transpose_cast<<<dim3(2, 8),  256, 0, stream>>>(W_out, WoutT, 128, 512, 0, 0);
    make_bcat<<<8, 256, 0, stream>>>(b_ih, b_hh, bcat);
    gemm64<<<dim3(8, 1024), 256, 0, stream>>>(ealb, UaT, bu, kpb, B_ * S_, 512, 512);
    transpose_kp8<<<512, 256, 0, stream>>>(kpb, kp8);
    init_state<<<1024, 256, 0, stream>>>(e_h, e_c, cst, hcbf, xeh, E);

    P pp;
    pp.target = target; pp.E = E; pp.bv = bv; pp.ba = ba; pp.bout = b_out;
    pp.vab = vab;
    pp.ea8 = ea8; pp.kp8 = kp8; pp.WaT = WaT; pp.WehT = WehT; pp.WctxT = WctxT; pp.WoutT = WoutT;
    pp.bcat = bcat; pp.qbf = qbf; pp.xeh = xeh; pp.ctxb = ctxb; pp.gpA = gpA; pp.gpB = gpB;
    pp.hcbf = hcbf; pp.h2bf = h2bf; pp.cst = cst;
    pp.out_logits = out_logits; pp.out_attn = out_attn;

    // q(0) + gp(0) from initial state
    kC<true><<<384, 256, 0, stream>>>(pp, 0);

    // ---- sequential decode: A(attn) -> B(fgate+LSTM) -> C(q ∥ pgateA ∥ pgateB ∥ out) ----
    for (int t = 0; t < T_; ++t) {
        kA<<<512, 256, 0, stream>>>(pp, t);
        kB<<<256, 256, 0, stream>>>(pp, t);
        kC<false><<<392, 256, 0, stream>>>(pp, t);
    }
    (void)n_in; (void)in_sizes; (void)out_size;
}